// Round 13
// baseline (3558.262 us; speedup 1.0000x reference)
//
#include <hip/hip_runtime.h>
#include <cmath>

typedef unsigned short u16;
typedef unsigned int   u32;

using bf16x8 = __attribute__((ext_vector_type(8))) short;   // 8 bf16 in 4 VGPRs
using f32x4  = __attribute__((ext_vector_type(4))) float;

#define S_LEN 2048
#define NHEAD 32
#define HDIM  160
#define HID   5120   // NHEAD*HDIM
#define NQKV  15360  // HID + 2*HID

__device__ __forceinline__ f32x4 mfma16(bf16x8 a, bf16x8 b, f32x4 c) {
  return __builtin_amdgcn_mfma_f32_16x16x32_bf16(a, b, c, 0, 0, 0);
}

__device__ __forceinline__ u16 f2bf(float f) {          // RNE f32->bf16
  u32 u = __builtin_bit_cast(u32, f);
  u += 0x7FFFu + ((u >> 16) & 1u);
  return (u16)(u >> 16);
}
__device__ __forceinline__ float bf2f(u16 h) {
  u32 u = ((u32)h) << 16;
  return __builtin_bit_cast(float, u);
}

// async global->LDS, 16B per lane; LDS dest is wave-uniform base + lane*16
__device__ __forceinline__ void gload16(const void* g, void* l) {
  __builtin_amdgcn_global_load_lds((const __attribute__((address_space(1))) void*)g,
                                   (__attribute__((address_space(3))) void*)l, 16, 0, 0);
}

// ---------------- fused f32 -> bf16 convert for hs + Wq + Wkv + Wd ------------
__global__ void cvt_all_kernel(const float* __restrict__ hs, const float* __restrict__ Wq,
                               const float* __restrict__ Wkv, const float* __restrict__ Wd,
                               u16* __restrict__ Xb, u16* __restrict__ Wqkvb,
                               u16* __restrict__ Wdb) {
  const int n_hs = S_LEN * HID / 8;          // 1,310,720
  const int n_q  = HID * HID / 8;            // 3,276,800
  const int n_kv = 2 * HID * HID / 8;        // 6,553,600
  const int n_d  = HID * HID / 8;            // 3,276,800
  const int total = n_hs + n_q + n_kv + n_d; // 14,417,920
  for (int i = blockIdx.x * 256 + threadIdx.x; i < total; i += gridDim.x * 256) {
    const float* src; u16* dst; int j = i;
    if (j < n_hs)                { src = hs;  dst = Xb; }
    else if ((j -= n_hs) < n_q)  { src = Wq;  dst = Wqkvb; }
    else if ((j -= n_q) < n_kv)  { src = Wkv; dst = Wqkvb + (size_t)HID * HID; }
    else { j -= n_kv;              src = Wd;  dst = Wdb; }
    float4 a = ((const float4*)src)[(size_t)j * 2];
    float4 b = ((const float4*)src)[(size_t)j * 2 + 1];
    uint4 o;
    o.x = (u32)f2bf(a.x) | ((u32)f2bf(a.y) << 16);
    o.y = (u32)f2bf(a.z) | ((u32)f2bf(a.w) << 16);
    o.z = (u32)f2bf(b.x) | ((u32)f2bf(b.y) << 16);
    o.w = (u32)f2bf(b.z) | ((u32)f2bf(b.w) << 16);
    ((uint4*)dst)[j] = o;
  }
}

// ---------------- RoPE table: tab[s][j] = (cos, sin), j<80 -------------------
// eff=8192 -> mscale=1.0, ntk_alpha=3, base=10000*3^(160/158).
__global__ void rope_table_kernel(float2* __restrict__ tab) {
  __shared__ double invf_s[80];
  int tid = threadIdx.x;
  if (tid < 80) {
    double base = 10000.0 * pow(3.0, 160.0 / 158.0);
    invf_s[tid] = pow(base, -((double)(2 * tid)) / 160.0);
  }
  __syncthreads();
  for (int i = blockIdx.x * 256 + tid; i < S_LEN * 80; i += gridDim.x * 256) {
    int s = i / 80, j = i % 80;
    double ang = fmod((double)s * invf_s[j], 6.283185307179586476925287);
    float a = (float)ang;
    tab[i] = make_float2(cosf(a), sinf(a));
  }
}

// ---------------- RoPE apply (Q and K in one launch) + head-major relayout ----
__global__ void rope_apply2_kernel(const u16* __restrict__ qkv, const float2* __restrict__ tab,
                                   u16* __restrict__ Qr, u16* __restrict__ Kr) {
  const int n = S_LEN * NHEAD * 80;                 // per-slice dword-pairs
  int i = blockIdx.x * 256 + threadIdx.x;
  bool isK = i >= n;
  if (isK) i -= n;
  const u16* src = qkv + (isK ? HID : 0);
  int headStride = isK ? 2 * HDIM : HDIM;
  u16* dst = isK ? Kr : Qr;

  int dp = i % 80; int sh = i / 80; int h = sh % NHEAD; int s = sh / NHEAD;
  int d = 2 * dp;
  const u16* row = src + (size_t)s * NQKV + h * headStride;
  u32 q01 = *(const u32*)&row[d];
  u32 p01 = *(const u32*)&row[d < 80 ? d + 80 : d - 80];
  int j = (d < 80) ? d : d - 80;
  float2 cs0 = tab[s * 80 + j];
  float2 cs1 = tab[s * 80 + j + 1];
  float q0 = bf2f((u16)(q01 & 0xffff)), q1 = bf2f((u16)(q01 >> 16));
  float p0 = bf2f((u16)(p01 & 0xffff)), p1 = bf2f((u16)(p01 >> 16));
  float sgn = (d < 80) ? -1.f : 1.f;                // out = x*cos + rot_half(x)*sin
  float o0 = q0 * cs0.x + sgn * p0 * cs0.y;
  float o1 = q1 * cs1.x + sgn * p1 * cs1.y;
  u32 o = (u32)f2bf(o0) | ((u32)f2bf(o1) << 16);
  *(u32*)&dst[((size_t)h * S_LEN + s) * HDIM + d] = o;
}

// ---------------- V transpose: v-slice of fused QKV -> Vt[h][d][s] -----------
__global__ void vtrans_kernel(const u16* __restrict__ src, u16* __restrict__ Vt, int rowStride) {
  __shared__ u16 T[HDIM][72];                       // pad 64->72 (2-way max on reads)
  int h = blockIdx.y; int s0 = blockIdx.x * 64; int tid = threadIdx.x;
  for (int i = tid; i < 64 * 80; i += 256) {
    int s = i / 80, dp = i % 80;
    u32 v = *(const u32*)&src[(size_t)(s0 + s) * rowStride + h * 320 + 2 * dp];
    T[2 * dp][s]     = (u16)(v & 0xffff);
    T[2 * dp + 1][s] = (u16)(v >> 16);
  }
  __syncthreads();
  for (int i = tid; i < HDIM * 32; i += 256) {
    int d = i / 32, sp = i % 32;
    u32 v = (u32)T[d][2 * sp] | ((u32)T[d][2 * sp + 1] << 16);
    *(u32*)&Vt[((size_t)h * HDIM + d) * S_LEN + s0 + 2 * sp] = v;
  }
}

// ---------------- GEMM 256(M)x128(N), BK=32, now 3 blocks/CU ------------------
// R11-measured 845 TF at 2 blocks/CU (Occupancy 42%, ~51% of the per-iter LDS
// floor -> barrier-skew-bound). VGPR=56, LDS 48KB: a 3rd block fits (144<=160,
// VGPR<<85-cap), so only __launch_bounds__ pinned it. (512,6) -> 3 blocks/CU.
template<int EPI>
__global__ __launch_bounds__(512, 6) void gemm256(
    const u16* __restrict__ A, const u16* __restrict__ Bm, void* __restrict__ Cout,
    int M, int N, int K, const float* __restrict__ bias, const float* __restrict__ resid)
{
  __shared__ u16 As[2][8192];    // [dbuf][256 rows x 32 cols]  16 KB/buf
  __shared__ u16 Bs[2][4096];    // [dbuf][128 rows x 32 cols]   8 KB/buf
  int tid = threadIdx.x;
  int w = tid >> 6, l = tid & 63, l15 = l & 15, l4 = l >> 4;
  int wr = w >> 1, wc = w & 1;   // 4 x 2 wave grid of 64x64 tiles

  int nbx = gridDim.x;
  int nwg = nbx * gridDim.y;
  int lin = blockIdx.y * nbx + blockIdx.x;
  int cpx = nwg >> 3;
  int swz = (lin & 7) * cpx + (lin >> 3);
  int bm = (swz / nbx) * 256, bn = (swz % nbx) * 128;

  int srow = tid >> 2;                                  // 0..127
  int scol = ((tid & 3) * 8) ^ ((srow & 8) ? 16 : 0);   // pre-swizzled source col
  const u16* gA0 = A + (size_t)(bm + srow) * K + scol;  // A rows 0..127
  const u16* gA1 = gA0 + (size_t)128 * K;               // A rows 128..255
  const u16* gB  = Bm + (size_t)(bn + srow) * K + scol; // B rows 0..127
  int w512 = w * 512;                                   // wave-uniform dest (elems)

  f32x4 acc[4][4];
#pragma unroll
  for (int i = 0; i < 4; i++)
#pragma unroll
    for (int j = 0; j < 4; j++) acc[i][j] = f32x4{0.f, 0.f, 0.f, 0.f};

  int cA = (l4 * 8) ^ ((l15 & 8) ? 16 : 0);             // read-side swizzle (const)
  const int NT = K >> 5;                                // 160 for K=5120
  int arow = wr * 64;
  int brow = wc * 64;

  auto STAGE = [&](int kt) { int p = kt & 1, ko = kt << 5;
    gload16(gA0 + ko, &As[p][w512]);
    gload16(gA1 + ko, &As[p][4096 + w512]);
    gload16(gB  + ko, &Bs[p][w512]);
  };

  STAGE(0);
  for (int kt = 0; kt < NT; ++kt) {
    int p = kt & 1;
    if (kt + 1 < NT) {
      STAGE(kt + 1);                       // writes buf p^1 (reads done iter kt-1)
      asm volatile("s_waitcnt vmcnt(3)" ::: "memory");   // tile kt landed (this wave)
    } else {
      asm volatile("s_waitcnt vmcnt(0)" ::: "memory");
    }
    __builtin_amdgcn_s_barrier();          // all waves' tile-kt loads visible

    bf16x8 aF[4], bF[4];
#pragma unroll
    for (int mi = 0; mi < 4; ++mi)
      aF[mi] = *(const bf16x8*)&As[p][(arow + mi * 16 + l15) * 32 + cA];
#pragma unroll
    for (int ni = 0; ni < 4; ++ni)
      bF[ni] = *(const bf16x8*)&Bs[p][(brow + ni * 16 + l15) * 32 + cA];
    __builtin_amdgcn_s_setprio(1);
#pragma unroll
    for (int mi = 0; mi < 4; ++mi)
#pragma unroll
      for (int ni = 0; ni < 4; ++ni)
        acc[mi][ni] = mfma16(aF[mi], bF[ni], acc[mi][ni]);
    __builtin_amdgcn_s_setprio(0);
    __builtin_amdgcn_s_barrier();          // tile-kt reads complete block-wide
  }

#pragma unroll
  for (int mi = 0; mi < 4; ++mi)
#pragma unroll
    for (int ni = 0; ni < 4; ++ni) {
      int row0 = bm + wr * 64 + mi * 16 + l4 * 4;
      int col  = bn + wc * 64 + ni * 16 + l15;
      if (EPI == 0) {
        u16* C = (u16*)Cout;
#pragma unroll
        for (int r = 0; r < 4; r++) C[(size_t)(row0 + r) * N + col] = f2bf(acc[mi][ni][r]);
      } else {
        float* C = (float*)Cout;
        float b = bias[col];
#pragma unroll
        for (int r = 0; r < 4; r++) {
          size_t idx = (size_t)(row0 + r) * N + col;
          C[idx] = acc[mi][ni][r] + b + resid[idx];
        }
      }
    }
}

// ---------------- GEMM 128x128 (proj) — dbuf + raw barriers + swizzle ---------
// Upgrades over the m97 form (R3-measured 694 TF, 2.6e7 bank conflicts):
// (1) double-buffered LDS + counted vmcnt(4) + raw s_barrier (removes the
//     __syncthreads vmcnt(0) drain — the documented ~20% stall; same proven
//     discipline as gemm256); (2) st_16x32 swizzle both sides (kills the 8-way
//     conflict: row-bit3 parity is preserved across +64-row halves so the same
//     constants as gemm256 apply). 32 KB LDS, (256,4) -> 4 blocks/CU.
template<int EPI>
__global__ __launch_bounds__(256, 4) void gemm_bt(
    const u16* __restrict__ A, const u16* __restrict__ Bm, void* __restrict__ Cout,
    int M, int N, int K, const float* __restrict__ bias, const float* __restrict__ resid)
{
  __shared__ u16 As[2][4096];    // [dbuf][128 rows x 32 cols]  8 KB/buf
  __shared__ u16 Bs[2][4096];
  int tid = threadIdx.x;
  int wv = tid >> 6, l = tid & 63, l15 = l & 15, l4 = l >> 4;
  int nbx = gridDim.x;
  int nwg = nbx * gridDim.y;
  int lin = blockIdx.y * nbx + blockIdx.x;
  int cpx = nwg >> 3;
  int swz = (lin & 7) * cpx + (lin >> 3);
  int bm = (swz / nbx) * 128, bn = (swz % nbx) * 128;

  f32x4 acc[4][4];
#pragma unroll
  for (int i = 0; i < 4; i++)
#pragma unroll
    for (int j = 0; j < 4; j++) acc[i][j] = f32x4{0.f, 0.f, 0.f, 0.f};

  int wm = (wv >> 1) * 64, wn = (wv & 1) * 64;
  int srow = tid >> 2;                                  // 0..63
  int scol = ((tid & 3) * 8) ^ ((srow & 8) ? 16 : 0);   // pre-swizzled source col
  const u16* gA = A  + (size_t)(bm + srow) * K + scol;  // rows 0..63 (+64 second)
  const u16* gB = Bm + (size_t)(bn + srow) * K + scol;
  int w512 = wv * 512;                                  // wave-uniform dest (elems)
  int cA = (l4 * 8) ^ ((l15 & 8) ? 16 : 0);             // read-side swizzle (const)
  const int NT = K >> 5;                                // 160

  auto STAGE = [&](int kt) { int p = kt & 1, ko = kt << 5;
    gload16(gA + ko,                    &As[p][w512]);
    gload16(gA + (size_t)64 * K + ko,   &As[p][2048 + w512]);
    gload16(gB + ko,                    &Bs[p][w512]);
    gload16(gB + (size_t)64 * K + ko,   &Bs[p][2048 + w512]);
  };

  STAGE(0);
  for (int kt = 0; kt < NT; ++kt) {
    int p = kt & 1;
    if (kt + 1 < NT) {
      STAGE(kt + 1);                      // writes buf p^1 (reads done iter kt-1)
      asm volatile("s_waitcnt vmcnt(4)" ::: "memory");   // tile kt landed
    } else {
      asm volatile("s_waitcnt vmcnt(0)" ::: "memory");
    }
    __builtin_amdgcn_s_barrier();

    bf16x8 af[4], bfr[4];
#pragma unroll
    for (int i = 0; i < 4; i++)
      af[i] = *(const bf16x8*)&As[p][(wm + i * 16 + l15) * 32 + cA];
#pragma unroll
    for (int i = 0; i < 4; i++)
      bfr[i] = *(const bf16x8*)&Bs[p][(wn + i * 16 + l15) * 32 + cA];
    __builtin_amdgcn_s_setprio(1);
#pragma unroll
    for (int mi = 0; mi < 4; mi++)
#pragma unroll
      for (int ni = 0; ni < 4; ni++) acc[mi][ni] = mfma16(af[mi], bfr[ni], acc[mi][ni]);
    __builtin_amdgcn_s_setprio(0);
    __builtin_amdgcn_s_barrier();
  }

#pragma unroll
  for (int mi = 0; mi < 4; mi++)
#pragma unroll
    for (int ni = 0; ni < 4; ni++) {
      int row0 = bm + wm + mi * 16 + l4 * 4;
      int col  = bn + wn + ni * 16 + l15;
      if (EPI == 0) {
        u16* C = (u16*)Cout;
#pragma unroll
        for (int r = 0; r < 4; r++) C[(size_t)(row0 + r) * N + col] = f2bf(acc[mi][ni][r]);
      } else {
        float* C = (float*)Cout;
        float b = bias[col];
#pragma unroll
        for (int r = 0; r < 4; r++) {
          size_t idx = (size_t)(row0 + r) * N + col;
          C[idx] = acc[mi][ni][r] + b + resid[idx];
        }
      }
    }
}

// ---------------- Flash attention v5: 4 waves x 32 q-rows ---------------------
__global__ __launch_bounds__(256, 2) void attn_kernel(
    const u16* __restrict__ Qr, const u16* __restrict__ Kr,
    const u16* __restrict__ Vt, u16* __restrict__ ctx)
{
  int lin = blockIdx.x;
  int h  = lin & 31;               // same head -> same XCD (lin%8 == h%8 both halves)
  int qx = (lin < 256) ? (15 - (lin >> 5)) : ((lin - 256) >> 5);
  int q0 = qx * 128;
  int tid = threadIdx.x;
  int w = tid >> 6, l = tid & 63, l15 = l & 15, l4 = l >> 4;
  int qb = q0 + w * 32;            // wave owns 32 q-rows

  __shared__ u16 Ks[64][164];      // 328B row stride: <=2-way on frag reads
  __shared__ u16 Vs[160][68];      // 136B row stride: conflict-free reads
  __shared__ u16 Plds[4][32][68];  // per-wave P tile (32 rows)

  const u16* Qh = Qr + (size_t)h * S_LEN * HDIM;
  const u16* Kh = Kr + (size_t)h * S_LEN * HDIM;
  const u16* Vh = Vt + (size_t)h * HDIM * S_LEN;

  bf16x8 aQ[2][5];
#pragma unroll
  for (int mi = 0; mi < 2; mi++)
#pragma unroll
    for (int kc = 0; kc < 5; kc++)
      aQ[mi][kc] = *(const bf16x8*)&Qh[(size_t)(qb + mi * 16 + l15) * HDIM + kc * 32 + l4 * 8];

  f32x4 accO[2][10];
#pragma unroll
  for (int mi = 0; mi < 2; mi++)
#pragma unroll
    for (int dt = 0; dt < 10; dt++) accO[mi][dt] = f32x4{0.f, 0.f, 0.f, 0.f};
  float mrun[2][4], lrun[2][4];
#pragma unroll
  for (int mi = 0; mi < 2; mi++)
#pragma unroll
    for (int r = 0; r < 4; r++) { mrun[mi][r] = -1e30f; lrun[mi][r] = 0.f; }

  const float c2 = 0.07905694150420949f * 1.44269504088896f;  // 1/sqrt(160)*log2(e)
  int Tend = 2 * qx + 2;           // k tiles cover k <= q0+127

  {
    uint4 rg[10];
#pragma unroll
    for (int i = 0; i < 10; i++) {
      int u = tid + 256 * i;
      if (u < 1280) { int row = u / 20, c = u % 20;
        rg[i] = *(const uint4*)&Kh[(size_t)row * HDIM + c * 8]; }
      else { int v = u - 1280; int row = v >> 3, c = v & 7;
        rg[i] = *(const uint4*)&Vh[(size_t)row * S_LEN + c * 8]; }
    }
#pragma unroll
    for (int i = 0; i < 10; i++) {
      int u = tid + 256 * i;
      if (u < 1280) { int row = u / 20, c = u % 20; *(uint4*)&Ks[row][c * 8] = rg[i]; }
      else { int v = u - 1280; int row = v >> 3, c = v & 7; *(uint4*)&Vs[row][c * 8] = rg[i]; }
    }
  }
  __syncthreads();

  for (int t = 0; t < Tend; ++t) {
    int k0 = t * 64;
    bool more = (t + 1 < Tend);
    uint4 rg[10];
    if (more) {                     // issue next-tile loads early (T14)
      int k1 = k0 + 64;
#pragma unroll
      for (int i = 0; i < 10; i++) {
        int u = tid + 256 * i;
        if (u < 1280) { int row = u / 20, c = u % 20;
          rg[i] = *(const uint4*)&Kh[(size_t)(k1 + row) * HDIM + c * 8]; }
        else { int v = u - 1280; int row = v >> 3, c = v & 7;
          rg[i] = *(const uint4*)&Vh[(size_t)row * S_LEN + k1 + c * 8]; }
      }
    }

    if (k0 <= qb + 31) {            // wave-active (causal tile skip)
      f32x4 s_[2][4];
#pragma unroll
      for (int mi = 0; mi < 2; mi++)
#pragma unroll
        for (int nt = 0; nt < 4; nt++) s_[mi][nt] = f32x4{0.f, 0.f, 0.f, 0.f};

#pragma unroll
      for (int kc = 0; kc < 5; kc++) {
        bf16x8 bK[4];
#pragma unroll
        for (int nt = 0; nt < 4; nt++)
          bK[nt] = *(const bf16x8*)&Ks[nt * 16 + l15][kc * 32 + l4 * 8];
        __builtin_amdgcn_s_setprio(1);
#pragma unroll
        for (int mi = 0; mi < 2; mi++)
#pragma unroll
          for (int nt = 0; nt < 4; nt++)
            s_[mi][nt] = mfma16(aQ[mi][kc], bK[nt], s_[mi][nt]);
        __builtin_amdgcn_s_setprio(0);
      }

      if (k0 + 63 > qb) {           // diagonal-region mask
#pragma unroll
        for (int mi = 0; mi < 2; mi++)
#pragma unroll
          for (int nt = 0; nt < 4; nt++)
#pragma unroll
            for (int r = 0; r < 4; r++) {
              int kk = k0 + nt * 16 + l15;
              int qq = qb + mi * 16 + l4 * 4 + r;
              if (kk > qq) s_[mi][nt][r] = -1e30f;
            }
      }

#pragma unroll
      for (int mi = 0; mi < 2; mi++) {
        float sf[4];
#pragma unroll
        for (int r = 0; r < 4; r++) {
          float v = fmaxf(fmaxf(s_[mi][0][r], s_[mi][1][r]), fmaxf(s_[mi][2][r], s_[mi][3][r]));
#pragma unroll
          for (int m = 1; m <= 8; m <<= 1) v = fmaxf(v, __shfl_xor(v, m));
          float mnew = fmaxf(mrun[mi][r], v);
          sf[r] = exp2f((mrun[mi][r] - mnew) * c2);
          mrun[mi][r] = mnew;
        }
        float rsum[4] = {0.f, 0.f, 0.f, 0.f};
#pragma unroll
        for (int nt = 0; nt < 4; nt++)
#pragma unroll
          for (int r = 0; r < 4; r++) {
            float p = exp2f((s_[mi][nt][r] - mrun[mi][r]) * c2);
            s_[mi][nt][r] = p;
            rsum[r] += p;
          }
#pragma unroll
        for (int r = 0; r < 4; r++) {
          float v = rsum[r];
#pragma unroll
          for (int m = 1; m <= 8; m <<= 1) v += __shfl_xor(v, m);
          lrun[mi][r] = lrun[mi][r] * sf[r] + v;
        }
#pragma unroll
        for (int dt = 0; dt < 10; dt++)
#pragma unroll
          for (int r = 0; r < 4; r++) accO[mi][dt][r] *= sf[r];
#pragma unroll
        for (int nt = 0; nt < 4; nt++)
#pragma unroll
          for (int r = 0; r < 4; r++)
            Plds[w][mi * 16 + l4 * 4 + r][nt * 16 + l15] = f2bf(s_[mi][nt][r]);
      }

      // PV: A = P (wave-local LDS), B = V rows (block LDS)
#pragma unroll
      for (int kc = 0; kc < 2; kc++) {
        bf16x8 aP[2];
#pragma unroll
        for (int mi = 0; mi < 2; mi++)
          aP[mi] = *(const bf16x8*)&Plds[w][mi * 16 + l15][kc * 32 + l4 * 8];
        bf16x8 bV[10];
#pragma unroll
        for (int dt = 0; dt < 10; dt++)
          bV[dt] = *(const bf16x8*)&Vs[dt * 16 + l15][kc * 32 + l4 * 8];
        __builtin_amdgcn_s_setprio(1);
#pragma unroll
        for (int dt = 0; dt < 10; dt++) {
          accO[0][dt] = mfma16(aP[0], bV[dt], accO[0][dt]);
          accO[1][dt] = mfma16(aP[1], bV[dt], accO[1][dt]);
        }
        __builtin_amdgcn_s_setprio(0);
      }
    }

    __builtin_amdgcn_s_barrier();   // raw: prefetch rg stays in flight
    if (more) {
#pragma unroll
      for (int i = 0; i < 10; i++) {
        int u = tid + 256 * i;
        if (u < 1280) { int row = u / 20, c = u % 20; *(uint4*)&Ks[row][c * 8] = rg[i]; }
        else { int v = u - 1280; int row = v >> 3, c = v & 7; *(uint4*)&Vs[row][c * 8] = rg[i]; }
      }
      asm volatile("s_waitcnt lgkmcnt(0)" ::: "memory");  // writes visible to other waves
    }
    __builtin_amdgcn_s_barrier();
  }

#pragma unroll
  for (int mi = 0; mi < 2; mi++) {
    float inv[4];
#pragma unroll
    for (int r = 0; r < 4; r++) inv[r] = 1.0f / lrun[mi][r];
#pragma unroll
    for (int dt = 0; dt < 10; dt++)
#pragma unroll
      for (int r = 0; r < 4; r++) {
        int q = qb + mi * 16 + l4 * 4 + r;
        ctx[(size_t)q * HID + h * HDIM + dt * 16 + l15] = f2bf(accO[mi][dt][r] * inv[r]);
      }
  }
}

// -----------------------------------------------------------------------------
extern "C" void kernel_launch(void* const* d_in, const int* in_sizes, int n_in,
                              void* d_out, int out_size, void* d_ws, size_t ws_size,
                              hipStream_t stream) {
  const float* hs    = (const float*)d_in[0];
  const float* resid = (const float*)d_in[1];
  // d_in[2] = attention_mask (causal triu) — implied by kernel, ignored
  const float* Wq  = (const float*)d_in[3];
  const float* Wkv = (const float*)d_in[4];
  const float* Wd  = (const float*)d_in[5];
  const float* bd  = (const float*)d_in[6];
  float* out = (float*)d_out;

  char* ws = (char*)d_ws;
  const size_t SH = (size_t)S_LEN * HID;          // 10,485,760
  u16* Xb     = (u16*)(ws);                        size_t off = SH * 2;
  u16* Wqkvb  = (u16*)(ws + off);                  off += (size_t)3 * HID * HID * 2; // [Wq rows | Wkv rows]
  u16* Wdb    = (u16*)(ws + off);                  off += (size_t)HID * HID * 2;
  u16* QKVraw = (u16*)(ws + off);                  off += (size_t)S_LEN * NQKV * 2;  // [2048][15360]
  u16* Qr     = (u16*)(ws + off);                  off += SH * 2;
  u16* Kr     = (u16*)(ws + off);                  off += SH * 2;
  u16* Vt     = (u16*)(ws + off);                  off += SH * 2;
  u16* ctx    = (u16*)(ws + off);                  off += SH * 2;
  float2* tab = (float2*)(ws + off);               off += (size_t)S_LEN * 80 * 8;

  // 1) one fused f32->bf16 pass: hs + Wq + Wkv + Wd
  cvt_all_kernel<<<2048, 256, 0, stream>>>(hs, Wq, Wkv, Wd, Xb, Wqkvb, Wdb);

  // 2) RoPE table
  rope_table_kernel<<<64, 256, 0, stream>>>(tab);

  // 3) fused QKV projection: [2048,15360] = Xb @ [Wq|Wkv]^T  (256x128 tiles)
  gemm256<0><<<dim3(NQKV / 128, S_LEN / 256), 512, 0, stream>>>(
      Xb, Wqkvb, QKVraw, S_LEN, NQKV, HID, nullptr, nullptr);

  // 4) RoPE Q+K in one launch; V transpose
  rope_apply2_kernel<<<2 * S_LEN * NHEAD * 80 / 256, 256, 0, stream>>>(QKVraw, tab, Qr, Kr);
  vtrans_kernel<<<dim3(S_LEN / 64, NHEAD), 256, 0, stream>>>(QKVraw + HID + HDIM, Vt, NQKV);

  // 5) attention (4 waves x 32 q-rows, balanced pairing, raw barriers)
  attn_kernel<<<512, 256, 0, stream>>>(Qr, Kr, Vt, ctx);

  // 6) output projection + bias + residual (dbuf + raw barriers + swizzle)
  gemm_bt<1><<<dim3(HID / 128, S_LEN / 128), 256, 0, stream>>>(
      ctx, Wdb, out, S_LEN, HID, HID, bd, resid);
}

// Round 14
// 957.413 us; speedup vs baseline: 3.7165x; 3.7165x over previous
//
#include <hip/hip_runtime.h>
#include <cmath>

typedef unsigned short u16;
typedef unsigned int   u32;

using bf16x8 = __attribute__((ext_vector_type(8))) short;   // 8 bf16 in 4 VGPRs
using f32x4  = __attribute__((ext_vector_type(4))) float;

#define S_LEN 2048
#define NHEAD 32
#define HDIM  160
#define HID   5120   // NHEAD*HDIM
#define NQKV  15360  // HID + 2*HID

__device__ __forceinline__ f32x4 mfma16(bf16x8 a, bf16x8 b, f32x4 c) {
  return __builtin_amdgcn_mfma_f32_16x16x32_bf16(a, b, c, 0, 0, 0);
}

__device__ __forceinline__ u16 f2bf(float f) {          // RNE f32->bf16
  u32 u = __builtin_bit_cast(u32, f);
  u += 0x7FFFu + ((u >> 16) & 1u);
  return (u16)(u >> 16);
}
__device__ __forceinline__ float bf2f(u16 h) {
  u32 u = ((u32)h) << 16;
  return __builtin_bit_cast(float, u);
}

// async global->LDS, 16B per lane; LDS dest is wave-uniform base + lane*16
__device__ __forceinline__ void gload16(const void* g, void* l) {
  __builtin_amdgcn_global_load_lds((const __attribute__((address_space(1))) void*)g,
                                   (__attribute__((address_space(3))) void*)l, 16, 0, 0);
}

// ---------------- fused f32 -> bf16 convert for hs + Wq + Wkv + Wd ------------
__global__ void cvt_all_kernel(const float* __restrict__ hs, const float* __restrict__ Wq,
                               const float* __restrict__ Wkv, const float* __restrict__ Wd,
                               u16* __restrict__ Xb, u16* __restrict__ Wqkvb,
                               u16* __restrict__ Wdb) {
  const int n_hs = S_LEN * HID / 8;          // 1,310,720
  const int n_q  = HID * HID / 8;            // 3,276,800
  const int n_kv = 2 * HID * HID / 8;        // 6,553,600
  const int n_d  = HID * HID / 8;            // 3,276,800
  const int total = n_hs + n_q + n_kv + n_d; // 14,417,920
  for (int i = blockIdx.x * 256 + threadIdx.x; i < total; i += gridDim.x * 256) {
    const float* src; u16* dst; int j = i;
    if (j < n_hs)                { src = hs;  dst = Xb; }
    else if ((j -= n_hs) < n_q)  { src = Wq;  dst = Wqkvb; }
    else if ((j -= n_q) < n_kv)  { src = Wkv; dst = Wqkvb + (size_t)HID * HID; }
    else { j -= n_kv;              src = Wd;  dst = Wdb; }
    float4 a = ((const float4*)src)[(size_t)j * 2];
    float4 b = ((const float4*)src)[(size_t)j * 2 + 1];
    uint4 o;
    o.x = (u32)f2bf(a.x) | ((u32)f2bf(a.y) << 16);
    o.y = (u32)f2bf(a.z) | ((u32)f2bf(a.w) << 16);
    o.z = (u32)f2bf(b.x) | ((u32)f2bf(b.y) << 16);
    o.w = (u32)f2bf(b.z) | ((u32)f2bf(b.w) << 16);
    ((uint4*)dst)[j] = o;
  }
}

// ---------------- RoPE table: tab[s][j] = (cos, sin), j<80 -------------------
// eff=8192 -> mscale=1.0, ntk_alpha=3, base=10000*3^(160/158).
__global__ void rope_table_kernel(float2* __restrict__ tab) {
  __shared__ double invf_s[80];
  int tid = threadIdx.x;
  if (tid < 80) {
    double base = 10000.0 * pow(3.0, 160.0 / 158.0);
    invf_s[tid] = pow(base, -((double)(2 * tid)) / 160.0);
  }
  __syncthreads();
  for (int i = blockIdx.x * 256 + tid; i < S_LEN * 80; i += gridDim.x * 256) {
    int s = i / 80, j = i % 80;
    double ang = fmod((double)s * invf_s[j], 6.283185307179586476925287);
    float a = (float)ang;
    tab[i] = make_float2(cosf(a), sinf(a));
  }
}

// ---------------- RoPE apply (Q and K in one launch) + head-major relayout ----
__global__ void rope_apply2_kernel(const u16* __restrict__ qkv, const float2* __restrict__ tab,
                                   u16* __restrict__ Qr, u16* __restrict__ Kr) {
  const int n = S_LEN * NHEAD * 80;                 // per-slice dword-pairs
  int i = blockIdx.x * 256 + threadIdx.x;
  bool isK = i >= n;
  if (isK) i -= n;
  const u16* src = qkv + (isK ? HID : 0);
  int headStride = isK ? 2 * HDIM : HDIM;
  u16* dst = isK ? Kr : Qr;

  int dp = i % 80; int sh = i / 80; int h = sh % NHEAD; int s = sh / NHEAD;
  int d = 2 * dp;
  const u16* row = src + (size_t)s * NQKV + h * headStride;
  u32 q01 = *(const u32*)&row[d];
  u32 p01 = *(const u32*)&row[d < 80 ? d + 80 : d - 80];
  int j = (d < 80) ? d : d - 80;
  float2 cs0 = tab[s * 80 + j];
  float2 cs1 = tab[s * 80 + j + 1];
  float q0 = bf2f((u16)(q01 & 0xffff)), q1 = bf2f((u16)(q01 >> 16));
  float p0 = bf2f((u16)(p01 & 0xffff)), p1 = bf2f((u16)(p01 >> 16));
  float sgn = (d < 80) ? -1.f : 1.f;                // out = x*cos + rot_half(x)*sin
  float o0 = q0 * cs0.x + sgn * p0 * cs0.y;
  float o1 = q1 * cs1.x + sgn * p1 * cs1.y;
  u32 o = (u32)f2bf(o0) | ((u32)f2bf(o1) << 16);
  *(u32*)&dst[((size_t)h * S_LEN + s) * HDIM + d] = o;
}

// ---------------- V transpose: v-slice of fused QKV -> Vt[h][d][s] -----------
__global__ void vtrans_kernel(const u16* __restrict__ src, u16* __restrict__ Vt, int rowStride) {
  __shared__ u16 T[HDIM][72];                       // pad 64->72 (2-way max on reads)
  int h = blockIdx.y; int s0 = blockIdx.x * 64; int tid = threadIdx.x;
  for (int i = tid; i < 64 * 80; i += 256) {
    int s = i / 80, dp = i % 80;
    u32 v = *(const u32*)&src[(size_t)(s0 + s) * rowStride + h * 320 + 2 * dp];
    T[2 * dp][s]     = (u16)(v & 0xffff);
    T[2 * dp + 1][s] = (u16)(v >> 16);
  }
  __syncthreads();
  for (int i = tid; i < HDIM * 32; i += 256) {
    int d = i / 32, sp = i % 32;
    u32 v = (u32)T[d][2 * sp] | ((u32)T[d][2 * sp + 1] << 16);
    *(u32*)&Vt[((size_t)h * HDIM + d) * S_LEN + s0 + 2 * sp] = v;
  }
}

// ---------------- GEMM 256(M)x128(N), BK=32, 2 blocks/CU ----------------------
// R11/R12-measured 845 TF (Occupancy 42%, 0 conflicts, VGPR 56). FROZEN at
// (512,4): R13 proved (512,6) forces the allocator to spill acc -> 13 GB of
// scratch traffic (VGPR 40, MfmaUtil 4.5%, 3.1 ms). Do not touch the bound.
template<int EPI>
__global__ __launch_bounds__(512, 4) void gemm256(
    const u16* __restrict__ A, const u16* __restrict__ Bm, void* __restrict__ Cout,
    int M, int N, int K, const float* __restrict__ bias, const float* __restrict__ resid)
{
  __shared__ u16 As[2][8192];    // [dbuf][256 rows x 32 cols]  16 KB/buf
  __shared__ u16 Bs[2][4096];    // [dbuf][128 rows x 32 cols]   8 KB/buf
  int tid = threadIdx.x;
  int w = tid >> 6, l = tid & 63, l15 = l & 15, l4 = l >> 4;
  int wr = w >> 1, wc = w & 1;   // 4 x 2 wave grid of 64x64 tiles

  int nbx = gridDim.x;
  int nwg = nbx * gridDim.y;
  int lin = blockIdx.y * nbx + blockIdx.x;
  int cpx = nwg >> 3;
  int swz = (lin & 7) * cpx + (lin >> 3);
  int bm = (swz / nbx) * 256, bn = (swz % nbx) * 128;

  int srow = tid >> 2;                                  // 0..127
  int scol = ((tid & 3) * 8) ^ ((srow & 8) ? 16 : 0);   // pre-swizzled source col
  const u16* gA0 = A + (size_t)(bm + srow) * K + scol;  // A rows 0..127
  const u16* gA1 = gA0 + (size_t)128 * K;               // A rows 128..255
  const u16* gB  = Bm + (size_t)(bn + srow) * K + scol; // B rows 0..127
  int w512 = w * 512;                                   // wave-uniform dest (elems)

  f32x4 acc[4][4];
#pragma unroll
  for (int i = 0; i < 4; i++)
#pragma unroll
    for (int j = 0; j < 4; j++) acc[i][j] = f32x4{0.f, 0.f, 0.f, 0.f};

  int cA = (l4 * 8) ^ ((l15 & 8) ? 16 : 0);             // read-side swizzle (const)
  const int NT = K >> 5;                                // 160 for K=5120
  int arow = wr * 64;
  int brow = wc * 64;

  auto STAGE = [&](int kt) { int p = kt & 1, ko = kt << 5;
    gload16(gA0 + ko, &As[p][w512]);
    gload16(gA1 + ko, &As[p][4096 + w512]);
    gload16(gB  + ko, &Bs[p][w512]);
  };

  STAGE(0);
  for (int kt = 0; kt < NT; ++kt) {
    int p = kt & 1;
    if (kt + 1 < NT) {
      STAGE(kt + 1);                       // writes buf p^1 (reads done iter kt-1)
      asm volatile("s_waitcnt vmcnt(3)" ::: "memory");   // tile kt landed (this wave)
    } else {
      asm volatile("s_waitcnt vmcnt(0)" ::: "memory");
    }
    __builtin_amdgcn_s_barrier();          // all waves' tile-kt loads visible

    bf16x8 aF[4], bF[4];
#pragma unroll
    for (int mi = 0; mi < 4; ++mi)
      aF[mi] = *(const bf16x8*)&As[p][(arow + mi * 16 + l15) * 32 + cA];
#pragma unroll
    for (int ni = 0; ni < 4; ++ni)
      bF[ni] = *(const bf16x8*)&Bs[p][(brow + ni * 16 + l15) * 32 + cA];
    __builtin_amdgcn_s_setprio(1);
#pragma unroll
    for (int mi = 0; mi < 4; ++mi)
#pragma unroll
      for (int ni = 0; ni < 4; ++ni)
        acc[mi][ni] = mfma16(aF[mi], bF[ni], acc[mi][ni]);
    __builtin_amdgcn_s_setprio(0);
    __builtin_amdgcn_s_barrier();          // tile-kt reads complete block-wide
  }

#pragma unroll
  for (int mi = 0; mi < 4; ++mi)
#pragma unroll
    for (int ni = 0; ni < 4; ++ni) {
      int row0 = bm + wr * 64 + mi * 16 + l4 * 4;
      int col  = bn + wc * 64 + ni * 16 + l15;
      if (EPI == 0) {
        u16* C = (u16*)Cout;
#pragma unroll
        for (int r = 0; r < 4; r++) C[(size_t)(row0 + r) * N + col] = f2bf(acc[mi][ni][r]);
      } else {
        float* C = (float*)Cout;
        float b = bias[col];
#pragma unroll
        for (int r = 0; r < 4; r++) {
          size_t idx = (size_t)(row0 + r) * N + col;
          C[idx] = acc[mi][ni][r] + b + resid[idx];
        }
      }
    }
}

// ---------------- GEMM 128x128 (proj) — dbuf + raw barriers + swizzle ---------
// Upgrades over the m97 form (R3-measured 694 TF, 2.6e7 bank conflicts):
// (1) double-buffered LDS + counted vmcnt(4) + raw s_barrier (removes the
//     __syncthreads vmcnt(0) drain); (2) st_16x32 swizzle both sides.
// 32 KB LDS, (256,4) -> VGPR cap 128 (demand ~111: no spill).
template<int EPI>
__global__ __launch_bounds__(256, 4) void gemm_bt(
    const u16* __restrict__ A, const u16* __restrict__ Bm, void* __restrict__ Cout,
    int M, int N, int K, const float* __restrict__ bias, const float* __restrict__ resid)
{
  __shared__ u16 As[2][4096];    // [dbuf][128 rows x 32 cols]  8 KB/buf
  __shared__ u16 Bs[2][4096];
  int tid = threadIdx.x;
  int wv = tid >> 6, l = tid & 63, l15 = l & 15, l4 = l >> 4;
  int nbx = gridDim.x;
  int nwg = nbx * gridDim.y;
  int lin = blockIdx.y * nbx + blockIdx.x;
  int cpx = nwg >> 3;
  int swz = (lin & 7) * cpx + (lin >> 3);
  int bm = (swz / nbx) * 128, bn = (swz % nbx) * 128;

  f32x4 acc[4][4];
#pragma unroll
  for (int i = 0; i < 4; i++)
#pragma unroll
    for (int j = 0; j < 4; j++) acc[i][j] = f32x4{0.f, 0.f, 0.f, 0.f};

  int wm = (wv >> 1) * 64, wn = (wv & 1) * 64;
  int srow = tid >> 2;                                  // 0..63
  int scol = ((tid & 3) * 8) ^ ((srow & 8) ? 16 : 0);   // pre-swizzled source col
  const u16* gA = A  + (size_t)(bm + srow) * K + scol;  // rows 0..63 (+64 second)
  const u16* gB = Bm + (size_t)(bn + srow) * K + scol;
  int w512 = wv * 512;                                  // wave-uniform dest (elems)
  int cA = (l4 * 8) ^ ((l15 & 8) ? 16 : 0);             // read-side swizzle (const)
  const int NT = K >> 5;                                // 160

  auto STAGE = [&](int kt) { int p = kt & 1, ko = kt << 5;
    gload16(gA + ko,                    &As[p][w512]);
    gload16(gA + (size_t)64 * K + ko,   &As[p][2048 + w512]);
    gload16(gB + ko,                    &Bs[p][w512]);
    gload16(gB + (size_t)64 * K + ko,   &Bs[p][2048 + w512]);
  };

  STAGE(0);
  for (int kt = 0; kt < NT; ++kt) {
    int p = kt & 1;
    if (kt + 1 < NT) {
      STAGE(kt + 1);                      // writes buf p^1 (reads done iter kt-1)
      asm volatile("s_waitcnt vmcnt(4)" ::: "memory");   // tile kt landed
    } else {
      asm volatile("s_waitcnt vmcnt(0)" ::: "memory");
    }
    __builtin_amdgcn_s_barrier();

    bf16x8 af[4], bfr[4];
#pragma unroll
    for (int i = 0; i < 4; i++)
      af[i] = *(const bf16x8*)&As[p][(wm + i * 16 + l15) * 32 + cA];
#pragma unroll
    for (int i = 0; i < 4; i++)
      bfr[i] = *(const bf16x8*)&Bs[p][(wn + i * 16 + l15) * 32 + cA];
    __builtin_amdgcn_s_setprio(1);
#pragma unroll
    for (int mi = 0; mi < 4; mi++)
#pragma unroll
      for (int ni = 0; ni < 4; ni++) acc[mi][ni] = mfma16(af[mi], bfr[ni], acc[mi][ni]);
    __builtin_amdgcn_s_setprio(0);
    __builtin_amdgcn_s_barrier();
  }

#pragma unroll
  for (int mi = 0; mi < 4; mi++)
#pragma unroll
    for (int ni = 0; ni < 4; ni++) {
      int row0 = bm + wm + mi * 16 + l4 * 4;
      int col  = bn + wn + ni * 16 + l15;
      if (EPI == 0) {
        u16* C = (u16*)Cout;
#pragma unroll
        for (int r = 0; r < 4; r++) C[(size_t)(row0 + r) * N + col] = f2bf(acc[mi][ni][r]);
      } else {
        float* C = (float*)Cout;
        float b = bias[col];
#pragma unroll
        for (int r = 0; r < 4; r++) {
          size_t idx = (size_t)(row0 + r) * N + col;
          C[idx] = acc[mi][ni][r] + b + resid[idx];
        }
      }
    }
}

// ---------------- Flash attention v5: 4 waves x 32 q-rows ---------------------
__global__ __launch_bounds__(256, 2) void attn_kernel(
    const u16* __restrict__ Qr, const u16* __restrict__ Kr,
    const u16* __restrict__ Vt, u16* __restrict__ ctx)
{
  int lin = blockIdx.x;
  int h  = lin & 31;               // same head -> same XCD (lin%8 == h%8 both halves)
  int qx = (lin < 256) ? (15 - (lin >> 5)) : ((lin - 256) >> 5);
  int q0 = qx * 128;
  int tid = threadIdx.x;
  int w = tid >> 6, l = tid & 63, l15 = l & 15, l4 = l >> 4;
  int qb = q0 + w * 32;            // wave owns 32 q-rows

  __shared__ u16 Ks[64][164];      // 328B row stride: <=2-way on frag reads
  __shared__ u16 Vs[160][68];      // 136B row stride: conflict-free reads
  __shared__ u16 Plds[4][32][68];  // per-wave P tile (32 rows)

  const u16* Qh = Qr + (size_t)h * S_LEN * HDIM;
  const u16* Kh = Kr + (size_t)h * S_LEN * HDIM;
  const u16* Vh = Vt + (size_t)h * HDIM * S_LEN;

  bf16x8 aQ[2][5];
#pragma unroll
  for (int mi = 0; mi < 2; mi++)
#pragma unroll
    for (int kc = 0; kc < 5; kc++)
      aQ[mi][kc] = *(const bf16x8*)&Qh[(size_t)(qb + mi * 16 + l15) * HDIM + kc * 32 + l4 * 8];

  f32x4 accO[2][10];
#pragma unroll
  for (int mi = 0; mi < 2; mi++)
#pragma unroll
    for (int dt = 0; dt < 10; dt++) accO[mi][dt] = f32x4{0.f, 0.f, 0.f, 0.f};
  float mrun[2][4], lrun[2][4];
#pragma unroll
  for (int mi = 0; mi < 2; mi++)
#pragma unroll
    for (int r = 0; r < 4; r++) { mrun[mi][r] = -1e30f; lrun[mi][r] = 0.f; }

  const float c2 = 0.07905694150420949f * 1.44269504088896f;  // 1/sqrt(160)*log2(e)
  int Tend = 2 * qx + 2;           // k tiles cover k <= q0+127

  {
    uint4 rg[10];
#pragma unroll
    for (int i = 0; i < 10; i++) {
      int u = tid + 256 * i;
      if (u < 1280) { int row = u / 20, c = u % 20;
        rg[i] = *(const uint4*)&Kh[(size_t)row * HDIM + c * 8]; }
      else { int v = u - 1280; int row = v >> 3, c = v & 7;
        rg[i] = *(const uint4*)&Vh[(size_t)row * S_LEN + c * 8]; }
    }
#pragma unroll
    for (int i = 0; i < 10; i++) {
      int u = tid + 256 * i;
      if (u < 1280) { int row = u / 20, c = u % 20; *(uint4*)&Ks[row][c * 8] = rg[i]; }
      else { int v = u - 1280; int row = v >> 3, c = v & 7; *(uint4*)&Vs[row][c * 8] = rg[i]; }
    }
  }
  __syncthreads();

  for (int t = 0; t < Tend; ++t) {
    int k0 = t * 64;
    bool more = (t + 1 < Tend);
    uint4 rg[10];
    if (more) {                     // issue next-tile loads early (T14)
      int k1 = k0 + 64;
#pragma unroll
      for (int i = 0; i < 10; i++) {
        int u = tid + 256 * i;
        if (u < 1280) { int row = u / 20, c = u % 20;
          rg[i] = *(const uint4*)&Kh[(size_t)(k1 + row) * HDIM + c * 8]; }
        else { int v = u - 1280; int row = v >> 3, c = v & 7;
          rg[i] = *(const uint4*)&Vh[(size_t)row * S_LEN + k1 + c * 8]; }
      }
    }

    if (k0 <= qb + 31) {            // wave-active (causal tile skip)
      f32x4 s_[2][4];
#pragma unroll
      for (int mi = 0; mi < 2; mi++)
#pragma unroll
        for (int nt = 0; nt < 4; nt++) s_[mi][nt] = f32x4{0.f, 0.f, 0.f, 0.f};

#pragma unroll
      for (int kc = 0; kc < 5; kc++) {
        bf16x8 bK[4];
#pragma unroll
        for (int nt = 0; nt < 4; nt++)
          bK[nt] = *(const bf16x8*)&Ks[nt * 16 + l15][kc * 32 + l4 * 8];
        __builtin_amdgcn_s_setprio(1);
#pragma unroll
        for (int mi = 0; mi < 2; mi++)
#pragma unroll
          for (int nt = 0; nt < 4; nt++)
            s_[mi][nt] = mfma16(aQ[mi][kc], bK[nt], s_[mi][nt]);
        __builtin_amdgcn_s_setprio(0);
      }

      if (k0 + 63 > qb) {           // diagonal-region mask
#pragma unroll
        for (int mi = 0; mi < 2; mi++)
#pragma unroll
          for (int nt = 0; nt < 4; nt++)
#pragma unroll
            for (int r = 0; r < 4; r++) {
              int kk = k0 + nt * 16 + l15;
              int qq = qb + mi * 16 + l4 * 4 + r;
              if (kk > qq) s_[mi][nt][r] = -1e30f;
            }
      }

#pragma unroll
      for (int mi = 0; mi < 2; mi++) {
        float sf[4];
#pragma unroll
        for (int r = 0; r < 4; r++) {
          float v = fmaxf(fmaxf(s_[mi][0][r], s_[mi][1][r]), fmaxf(s_[mi][2][r], s_[mi][3][r]));
#pragma unroll
          for (int m = 1; m <= 8; m <<= 1) v = fmaxf(v, __shfl_xor(v, m));
          float mnew = fmaxf(mrun[mi][r], v);
          sf[r] = exp2f((mrun[mi][r] - mnew) * c2);
          mrun[mi][r] = mnew;
        }
        float rsum[4] = {0.f, 0.f, 0.f, 0.f};
#pragma unroll
        for (int nt = 0; nt < 4; nt++)
#pragma unroll
          for (int r = 0; r < 4; r++) {
            float p = exp2f((s_[mi][nt][r] - mrun[mi][r]) * c2);
            s_[mi][nt][r] = p;
            rsum[r] += p;
          }
#pragma unroll
        for (int r = 0; r < 4; r++) {
          float v = rsum[r];
#pragma unroll
          for (int m = 1; m <= 8; m <<= 1) v += __shfl_xor(v, m);
          lrun[mi][r] = lrun[mi][r] * sf[r] + v;
        }
#pragma unroll
        for (int dt = 0; dt < 10; dt++)
#pragma unroll
          for (int r = 0; r < 4; r++) accO[mi][dt][r] *= sf[r];
#pragma unroll
        for (int nt = 0; nt < 4; nt++)
#pragma unroll
          for (int r = 0; r < 4; r++)
            Plds[w][mi * 16 + l4 * 4 + r][nt * 16 + l15] = f2bf(s_[mi][nt][r]);
      }

      // PV: A = P (wave-local LDS), B = V rows (block LDS)
#pragma unroll
      for (int kc = 0; kc < 2; kc++) {
        bf16x8 aP[2];
#pragma unroll
        for (int mi = 0; mi < 2; mi++)
          aP[mi] = *(const bf16x8*)&Plds[w][mi * 16 + l15][kc * 32 + l4 * 8];
        bf16x8 bV[10];
#pragma unroll
        for (int dt = 0; dt < 10; dt++)
          bV[dt] = *(const bf16x8*)&Vs[dt * 16 + l15][kc * 32 + l4 * 8];
        __builtin_amdgcn_s_setprio(1);
#pragma unroll
        for (int dt = 0; dt < 10; dt++) {
          accO[0][dt] = mfma16(aP[0], bV[dt], accO[0][dt]);
          accO[1][dt] = mfma16(aP[1], bV[dt], accO[1][dt]);
        }
        __builtin_amdgcn_s_setprio(0);
      }
    }

    __builtin_amdgcn_s_barrier();   // raw: prefetch rg stays in flight
    if (more) {
#pragma unroll
      for (int i = 0; i < 10; i++) {
        int u = tid + 256 * i;
        if (u < 1280) { int row = u / 20, c = u % 20; *(uint4*)&Ks[row][c * 8] = rg[i]; }
        else { int v = u - 1280; int row = v >> 3, c = v & 7; *(uint4*)&Vs[row][c * 8] = rg[i]; }
      }
      asm volatile("s_waitcnt lgkmcnt(0)" ::: "memory");  // writes visible to other waves
    }
    __builtin_amdgcn_s_barrier();
  }

#pragma unroll
  for (int mi = 0; mi < 2; mi++) {
    float inv[4];
#pragma unroll
    for (int r = 0; r < 4; r++) inv[r] = 1.0f / lrun[mi][r];
#pragma unroll
    for (int dt = 0; dt < 10; dt++)
#pragma unroll
      for (int r = 0; r < 4; r++) {
        int q = qb + mi * 16 + l4 * 4 + r;
        ctx[(size_t)q * HID + h * HDIM + dt * 16 + l15] = f2bf(accO[mi][dt][r] * inv[r]);
      }
  }
}

// -----------------------------------------------------------------------------
extern "C" void kernel_launch(void* const* d_in, const int* in_sizes, int n_in,
                              void* d_out, int out_size, void* d_ws, size_t ws_size,
                              hipStream_t stream) {
  const float* hs    = (const float*)d_in[0];
  const float* resid = (const float*)d_in[1];
  // d_in[2] = attention_mask (causal triu) — implied by kernel, ignored
  const float* Wq  = (const float*)d_in[3];
  const float* Wkv = (const float*)d_in[4];
  const float* Wd  = (const float*)d_in[5];
  const float* bd  = (const float*)d_in[6];
  float* out = (float*)d_out;

  char* ws = (char*)d_ws;
  const size_t SH = (size_t)S_LEN * HID;          // 10,485,760
  u16* Xb     = (u16*)(ws);                        size_t off = SH * 2;
  u16* Wqkvb  = (u16*)(ws + off);                  off += (size_t)3 * HID * HID * 2; // [Wq rows | Wkv rows]
  u16* Wdb    = (u16*)(ws + off);                  off += (size_t)HID * HID * 2;
  u16* QKVraw = (u16*)(ws + off);                  off += (size_t)S_LEN * NQKV * 2;  // [2048][15360]
  u16* Qr     = (u16*)(ws + off);                  off += SH * 2;
  u16* Kr     = (u16*)(ws + off);                  off += SH * 2;
  u16* Vt     = (u16*)(ws + off);                  off += SH * 2;
  u16* ctx    = (u16*)(ws + off);                  off += SH * 2;
  float2* tab = (float2*)(ws + off);               off += (size_t)S_LEN * 80 * 8;

  // 1) one fused f32->bf16 pass: hs + Wq + Wkv + Wd
  cvt_all_kernel<<<2048, 256, 0, stream>>>(hs, Wq, Wkv, Wd, Xb, Wqkvb, Wdb);

  // 2) RoPE table
  rope_table_kernel<<<64, 256, 0, stream>>>(tab);

  // 3) fused QKV projection: [2048,15360] = Xb @ [Wq|Wkv]^T  (256x128 tiles)
  gemm256<0><<<dim3(NQKV / 128, S_LEN / 256), 512, 0, stream>>>(
      Xb, Wqkvb, QKVraw, S_LEN, NQKV, HID, nullptr, nullptr);

  // 4) RoPE Q+K in one launch; V transpose
  rope_apply2_kernel<<<2 * S_LEN * NHEAD * 80 / 256, 256, 0, stream>>>(QKVraw, tab, Qr, Kr);
  vtrans_kernel<<<dim3(S_LEN / 64, NHEAD), 256, 0, stream>>>(QKVraw + HID + HDIM, Vt, NQKV);

  // 5) attention (4 waves x 32 q-rows, balanced pairing, raw barriers)
  attn_kernel<<<512, 256, 0, stream>>>(Qr, Kr, Vt, ctx);

  // 6) output projection + bias + residual (dbuf + raw barriers + swizzle)
  gemm_bt<1><<<dim3(HID / 128, S_LEN / 128), 256, 0, stream>>>(
      ctx, Wdb, out, S_LEN, HID, HID, bd, resid);
}

// Round 15
// 951.769 us; speedup vs baseline: 3.7386x; 1.0059x over previous
//
#include <hip/hip_runtime.h>
#include <cmath>

typedef unsigned short u16;
typedef unsigned int   u32;

using bf16x8 = __attribute__((ext_vector_type(8))) short;   // 8 bf16 in 4 VGPRs
using f32x4  = __attribute__((ext_vector_type(4))) float;

#define S_LEN 2048
#define NHEAD 32
#define HDIM  160
#define HID   5120   // NHEAD*HDIM
#define NQKV  15360  // HID + 2*HID

__device__ __forceinline__ f32x4 mfma16(bf16x8 a, bf16x8 b, f32x4 c) {
  return __builtin_amdgcn_mfma_f32_16x16x32_bf16(a, b, c, 0, 0, 0);
}

__device__ __forceinline__ u16 f2bf(float f) {          // RNE f32->bf16
  u32 u = __builtin_bit_cast(u32, f);
  u += 0x7FFFu + ((u >> 16) & 1u);
  return (u16)(u >> 16);
}
__device__ __forceinline__ float bf2f(u16 h) {
  u32 u = ((u32)h) << 16;
  return __builtin_bit_cast(float, u);
}

// async global->LDS, 16B per lane; LDS dest is wave-uniform base + lane*16
__device__ __forceinline__ void gload16(const void* g, void* l) {
  __builtin_amdgcn_global_load_lds((const __attribute__((address_space(1))) void*)g,
                                   (__attribute__((address_space(3))) void*)l, 16, 0, 0);
}

// ---------------- fused f32 -> bf16 convert for hs + Wq + Wkv + Wd ------------
__global__ void cvt_all_kernel(const float* __restrict__ hs, const float* __restrict__ Wq,
                               const float* __restrict__ Wkv, const float* __restrict__ Wd,
                               u16* __restrict__ Xb, u16* __restrict__ Wqkvb,
                               u16* __restrict__ Wdb) {
  const int n_hs = S_LEN * HID / 8;          // 1,310,720
  const int n_q  = HID * HID / 8;            // 3,276,800
  const int n_kv = 2 * HID * HID / 8;        // 6,553,600
  const int n_d  = HID * HID / 8;            // 3,276,800
  const int total = n_hs + n_q + n_kv + n_d; // 14,417,920
  for (int i = blockIdx.x * 256 + threadIdx.x; i < total; i += gridDim.x * 256) {
    const float* src; u16* dst; int j = i;
    if (j < n_hs)                { src = hs;  dst = Xb; }
    else if ((j -= n_hs) < n_q)  { src = Wq;  dst = Wqkvb; }
    else if ((j -= n_q) < n_kv)  { src = Wkv; dst = Wqkvb + (size_t)HID * HID; }
    else { j -= n_kv;              src = Wd;  dst = Wdb; }
    float4 a = ((const float4*)src)[(size_t)j * 2];
    float4 b = ((const float4*)src)[(size_t)j * 2 + 1];
    uint4 o;
    o.x = (u32)f2bf(a.x) | ((u32)f2bf(a.y) << 16);
    o.y = (u32)f2bf(a.z) | ((u32)f2bf(a.w) << 16);
    o.z = (u32)f2bf(b.x) | ((u32)f2bf(b.y) << 16);
    o.w = (u32)f2bf(b.z) | ((u32)f2bf(b.w) << 16);
    ((uint4*)dst)[j] = o;
  }
}

// ---------------- RoPE table: tab[s][j] = (cos, sin), j<80 -------------------
// eff=8192 -> mscale=1.0, ntk_alpha=3, base=10000*3^(160/158).
__global__ void rope_table_kernel(float2* __restrict__ tab) {
  __shared__ double invf_s[80];
  int tid = threadIdx.x;
  if (tid < 80) {
    double base = 10000.0 * pow(3.0, 160.0 / 158.0);
    invf_s[tid] = pow(base, -((double)(2 * tid)) / 160.0);
  }
  __syncthreads();
  for (int i = blockIdx.x * 256 + tid; i < S_LEN * 80; i += gridDim.x * 256) {
    int s = i / 80, j = i % 80;
    double ang = fmod((double)s * invf_s[j], 6.283185307179586476925287);
    float a = (float)ang;
    tab[i] = make_float2(cosf(a), sinf(a));
  }
}

// ---------------- RoPE apply (Q and K in one launch) + head-major relayout ----
__global__ void rope_apply2_kernel(const u16* __restrict__ qkv, const float2* __restrict__ tab,
                                   u16* __restrict__ Qr, u16* __restrict__ Kr) {
  const int n = S_LEN * NHEAD * 80;                 // per-slice dword-pairs
  int i = blockIdx.x * 256 + threadIdx.x;
  bool isK = i >= n;
  if (isK) i -= n;
  const u16* src = qkv + (isK ? HID : 0);
  int headStride = isK ? 2 * HDIM : HDIM;
  u16* dst = isK ? Kr : Qr;

  int dp = i % 80; int sh = i / 80; int h = sh % NHEAD; int s = sh / NHEAD;
  int d = 2 * dp;
  const u16* row = src + (size_t)s * NQKV + h * headStride;
  u32 q01 = *(const u32*)&row[d];
  u32 p01 = *(const u32*)&row[d < 80 ? d + 80 : d - 80];
  int j = (d < 80) ? d : d - 80;
  float2 cs0 = tab[s * 80 + j];
  float2 cs1 = tab[s * 80 + j + 1];
  float q0 = bf2f((u16)(q01 & 0xffff)), q1 = bf2f((u16)(q01 >> 16));
  float p0 = bf2f((u16)(p01 & 0xffff)), p1 = bf2f((u16)(p01 >> 16));
  float sgn = (d < 80) ? -1.f : 1.f;                // out = x*cos + rot_half(x)*sin
  float o0 = q0 * cs0.x + sgn * p0 * cs0.y;
  float o1 = q1 * cs1.x + sgn * p1 * cs1.y;
  u32 o = (u32)f2bf(o0) | ((u32)f2bf(o1) << 16);
  *(u32*)&dst[((size_t)h * S_LEN + s) * HDIM + d] = o;
}

// ---------------- V transpose: v-slice of fused QKV -> Vt[h][d][s] -----------
__global__ void vtrans_kernel(const u16* __restrict__ src, u16* __restrict__ Vt, int rowStride) {
  __shared__ u16 T[HDIM][72];                       // pad 64->72 (2-way max on reads)
  int h = blockIdx.y; int s0 = blockIdx.x * 64; int tid = threadIdx.x;
  for (int i = tid; i < 64 * 80; i += 256) {
    int s = i / 80, dp = i % 80;
    u32 v = *(const u32*)&src[(size_t)(s0 + s) * rowStride + h * 320 + 2 * dp];
    T[2 * dp][s]     = (u16)(v & 0xffff);
    T[2 * dp + 1][s] = (u16)(v >> 16);
  }
  __syncthreads();
  for (int i = tid; i < HDIM * 32; i += 256) {
    int d = i / 32, sp = i % 32;
    u32 v = (u32)T[d][2 * sp] | ((u32)T[d][2 * sp + 1] << 16);
    *(u32*)&Vt[((size_t)h * HDIM + d) * S_LEN + s0 + 2 * sp] = v;
  }
}

// ---------------- GEMM 256(M)x128(N), BK=32, 2 blocks/CU ----------------------
// R11/R12-measured 845 TF (Occupancy 42%, 0 conflicts, VGPR 56). FROZEN at
// (512,4): R13 proved (512,6) forces acc spill (13 GB scratch, 3.1 ms).
template<int EPI>
__global__ __launch_bounds__(512, 4) void gemm256(
    const u16* __restrict__ A, const u16* __restrict__ Bm, void* __restrict__ Cout,
    int M, int N, int K, const float* __restrict__ bias, const float* __restrict__ resid)
{
  __shared__ u16 As[2][8192];    // [dbuf][256 rows x 32 cols]  16 KB/buf
  __shared__ u16 Bs[2][4096];    // [dbuf][128 rows x 32 cols]   8 KB/buf
  int tid = threadIdx.x;
  int w = tid >> 6, l = tid & 63, l15 = l & 15, l4 = l >> 4;
  int wr = w >> 1, wc = w & 1;   // 4 x 2 wave grid of 64x64 tiles

  int nbx = gridDim.x;
  int nwg = nbx * gridDim.y;
  int lin = blockIdx.y * nbx + blockIdx.x;
  int cpx = nwg >> 3;
  int swz = (lin & 7) * cpx + (lin >> 3);
  int bm = (swz / nbx) * 256, bn = (swz % nbx) * 128;

  int srow = tid >> 2;                                  // 0..127
  int scol = ((tid & 3) * 8) ^ ((srow & 8) ? 16 : 0);   // pre-swizzled source col
  const u16* gA0 = A + (size_t)(bm + srow) * K + scol;  // A rows 0..127
  const u16* gA1 = gA0 + (size_t)128 * K;               // A rows 128..255
  const u16* gB  = Bm + (size_t)(bn + srow) * K + scol; // B rows 0..127
  int w512 = w * 512;                                   // wave-uniform dest (elems)

  f32x4 acc[4][4];
#pragma unroll
  for (int i = 0; i < 4; i++)
#pragma unroll
    for (int j = 0; j < 4; j++) acc[i][j] = f32x4{0.f, 0.f, 0.f, 0.f};

  int cA = (l4 * 8) ^ ((l15 & 8) ? 16 : 0);             // read-side swizzle (const)
  const int NT = K >> 5;                                // 160 for K=5120
  int arow = wr * 64;
  int brow = wc * 64;

  auto STAGE = [&](int kt) { int p = kt & 1, ko = kt << 5;
    gload16(gA0 + ko, &As[p][w512]);
    gload16(gA1 + ko, &As[p][4096 + w512]);
    gload16(gB  + ko, &Bs[p][w512]);
  };

  STAGE(0);
  for (int kt = 0; kt < NT; ++kt) {
    int p = kt & 1;
    if (kt + 1 < NT) {
      STAGE(kt + 1);                       // writes buf p^1 (reads done iter kt-1)
      asm volatile("s_waitcnt vmcnt(3)" ::: "memory");   // tile kt landed (this wave)
    } else {
      asm volatile("s_waitcnt vmcnt(0)" ::: "memory");
    }
    __builtin_amdgcn_s_barrier();          // all waves' tile-kt loads visible

    bf16x8 aF[4], bF[4];
#pragma unroll
    for (int mi = 0; mi < 4; ++mi)
      aF[mi] = *(const bf16x8*)&As[p][(arow + mi * 16 + l15) * 32 + cA];
#pragma unroll
    for (int ni = 0; ni < 4; ++ni)
      bF[ni] = *(const bf16x8*)&Bs[p][(brow + ni * 16 + l15) * 32 + cA];
    __builtin_amdgcn_s_setprio(1);
#pragma unroll
    for (int mi = 0; mi < 4; ++mi)
#pragma unroll
      for (int ni = 0; ni < 4; ++ni)
        acc[mi][ni] = mfma16(aF[mi], bF[ni], acc[mi][ni]);
    __builtin_amdgcn_s_setprio(0);
    __builtin_amdgcn_s_barrier();          // tile-kt reads complete block-wide
  }

#pragma unroll
  for (int mi = 0; mi < 4; ++mi)
#pragma unroll
    for (int ni = 0; ni < 4; ++ni) {
      int row0 = bm + wr * 64 + mi * 16 + l4 * 4;
      int col  = bn + wc * 64 + ni * 16 + l15;
      if (EPI == 0) {
        u16* C = (u16*)Cout;
#pragma unroll
        for (int r = 0; r < 4; r++) C[(size_t)(row0 + r) * N + col] = f2bf(acc[mi][ni][r]);
      } else {
        float* C = (float*)Cout;
        float b = bias[col];
#pragma unroll
        for (int r = 0; r < 4; r++) {
          size_t idx = (size_t)(row0 + r) * N + col;
          C[idx] = acc[mi][ni][r] + b + resid[idx];
        }
      }
    }
}

// ---------------- GEMM 128x128 (m97 structure; proj) -------------------------
// R12-measured best (R14 proved the dbuf+swizzle variant is 13 µs slower at
// this shape: 640 blocks / 2-3 blocks/CU of TLP already hide the barrier drain).
template<int EPI>
__global__ __launch_bounds__(256, 2) void gemm_bt(
    const u16* __restrict__ A, const u16* __restrict__ Bm, void* __restrict__ Cout,
    int M, int N, int K, const float* __restrict__ bias, const float* __restrict__ resid)
{
  int tid = threadIdx.x;
  int wv = tid >> 6, l = tid & 63, l15 = l & 15, l4 = l >> 4;
  int nbx = gridDim.x;
  int nwg = nbx * gridDim.y;
  int lin = blockIdx.y * nbx + blockIdx.x;
  int cpx = nwg >> 3;
  int swz = (lin & 7) * cpx + (lin >> 3);
  int bm = (swz / nbx) * 128, bn = (swz % nbx) * 128;

  __shared__ u16 As[128 * 32], Bs[128 * 32];
  f32x4 acc[4][4];
#pragma unroll
  for (int i = 0; i < 4; i++)
#pragma unroll
    for (int j = 0; j < 4; j++) acc[i][j] = f32x4{0.f, 0.f, 0.f, 0.f};

  int wm = (wv >> 1) * 64, wn = (wv & 1) * 64;
  const u16* gA = A + (size_t)(bm + (tid >> 2)) * K + (tid & 3) * 8;
  const u16* gB = Bm + (size_t)(bn + (tid >> 2)) * K + (tid & 3) * 8;
  u16* ldsA = As + wv * 16 * 32;
  u16* ldsB = Bs + wv * 16 * 32;

  for (int k0 = 0; k0 < K; k0 += 32) {
    __syncthreads();
    gload16(gA + k0, ldsA);
    gload16(gA + (size_t)64 * K + k0, ldsA + 64 * 32);
    gload16(gB + k0, ldsB);
    gload16(gB + (size_t)64 * K + k0, ldsB + 64 * 32);
    __syncthreads();
    bf16x8 af[4], bfr[4];
#pragma unroll
    for (int i = 0; i < 4; i++) af[i] = *(const bf16x8*)&As[(wm + i * 16 + l15) * 32 + l4 * 8];
#pragma unroll
    for (int i = 0; i < 4; i++) bfr[i] = *(const bf16x8*)&Bs[(wn + i * 16 + l15) * 32 + l4 * 8];
#pragma unroll
    for (int mi = 0; mi < 4; mi++)
#pragma unroll
      for (int ni = 0; ni < 4; ni++) acc[mi][ni] = mfma16(af[mi], bfr[ni], acc[mi][ni]);
  }

#pragma unroll
  for (int mi = 0; mi < 4; mi++)
#pragma unroll
    for (int ni = 0; ni < 4; ni++) {
      int row0 = bm + wm + mi * 16 + l4 * 4;
      int col  = bn + wn + ni * 16 + l15;
      if (EPI == 0) {
        u16* C = (u16*)Cout;
#pragma unroll
        for (int r = 0; r < 4; r++) C[(size_t)(row0 + r) * N + col] = f2bf(acc[mi][ni][r]);
      } else {
        float* C = (float*)Cout;
        float b = bias[col];
#pragma unroll
        for (int r = 0; r < 4; r++) {
          size_t idx = (size_t)(row0 + r) * N + col;
          C[idx] = acc[mi][ni][r] + b + resid[idx];
        }
      }
    }
}

// ---------------- Flash attention v5: 4 waves x 32 q-rows ---------------------
__global__ __launch_bounds__(256, 2) void attn_kernel(
    const u16* __restrict__ Qr, const u16* __restrict__ Kr,
    const u16* __restrict__ Vt, u16* __restrict__ ctx)
{
  int lin = blockIdx.x;
  int h  = lin & 31;               // same head -> same XCD (lin%8 == h%8 both halves)
  int qx = (lin < 256) ? (15 - (lin >> 5)) : ((lin - 256) >> 5);
  int q0 = qx * 128;
  int tid = threadIdx.x;
  int w = tid >> 6, l = tid & 63, l15 = l & 15, l4 = l >> 4;
  int qb = q0 + w * 32;            // wave owns 32 q-rows

  __shared__ u16 Ks[64][164];      // 328B row stride: <=2-way on frag reads
  __shared__ u16 Vs[160][68];      // 136B row stride: conflict-free reads
  __shared__ u16 Plds[4][32][68];  // per-wave P tile (32 rows)

  const u16* Qh = Qr + (size_t)h * S_LEN * HDIM;
  const u16* Kh = Kr + (size_t)h * S_LEN * HDIM;
  const u16* Vh = Vt + (size_t)h * HDIM * S_LEN;

  bf16x8 aQ[2][5];
#pragma unroll
  for (int mi = 0; mi < 2; mi++)
#pragma unroll
    for (int kc = 0; kc < 5; kc++)
      aQ[mi][kc] = *(const bf16x8*)&Qh[(size_t)(qb + mi * 16 + l15) * HDIM + kc * 32 + l4 * 8];

  f32x4 accO[2][10];
#pragma unroll
  for (int mi = 0; mi < 2; mi++)
#pragma unroll
    for (int dt = 0; dt < 10; dt++) accO[mi][dt] = f32x4{0.f, 0.f, 0.f, 0.f};
  float mrun[2][4], lrun[2][4];
#pragma unroll
  for (int mi = 0; mi < 2; mi++)
#pragma unroll
    for (int r = 0; r < 4; r++) { mrun[mi][r] = -1e30f; lrun[mi][r] = 0.f; }

  const float c2 = 0.07905694150420949f * 1.44269504088896f;  // 1/sqrt(160)*log2(e)
  int Tend = 2 * qx + 2;           // k tiles cover k <= q0+127

  {
    uint4 rg[10];
#pragma unroll
    for (int i = 0; i < 10; i++) {
      int u = tid + 256 * i;
      if (u < 1280) { int row = u / 20, c = u % 20;
        rg[i] = *(const uint4*)&Kh[(size_t)row * HDIM + c * 8]; }
      else { int v = u - 1280; int row = v >> 3, c = v & 7;
        rg[i] = *(const uint4*)&Vh[(size_t)row * S_LEN + c * 8]; }
    }
#pragma unroll
    for (int i = 0; i < 10; i++) {
      int u = tid + 256 * i;
      if (u < 1280) { int row = u / 20, c = u % 20; *(uint4*)&Ks[row][c * 8] = rg[i]; }
      else { int v = u - 1280; int row = v >> 3, c = v & 7; *(uint4*)&Vs[row][c * 8] = rg[i]; }
    }
  }
  __syncthreads();

  for (int t = 0; t < Tend; ++t) {
    int k0 = t * 64;
    bool more = (t + 1 < Tend);
    uint4 rg[10];
    if (more) {                     // issue next-tile loads early (T14)
      int k1 = k0 + 64;
#pragma unroll
      for (int i = 0; i < 10; i++) {
        int u = tid + 256 * i;
        if (u < 1280) { int row = u / 20, c = u % 20;
          rg[i] = *(const uint4*)&Kh[(size_t)(k1 + row) * HDIM + c * 8]; }
        else { int v = u - 1280; int row = v >> 3, c = v & 7;
          rg[i] = *(const uint4*)&Vh[(size_t)row * S_LEN + k1 + c * 8]; }
      }
    }

    if (k0 <= qb + 31) {            // wave-active (causal tile skip)
      f32x4 s_[2][4];
#pragma unroll
      for (int mi = 0; mi < 2; mi++)
#pragma unroll
        for (int nt = 0; nt < 4; nt++) s_[mi][nt] = f32x4{0.f, 0.f, 0.f, 0.f};

#pragma unroll
      for (int kc = 0; kc < 5; kc++) {
        bf16x8 bK[4];
#pragma unroll
        for (int nt = 0; nt < 4; nt++)
          bK[nt] = *(const bf16x8*)&Ks[nt * 16 + l15][kc * 32 + l4 * 8];
        __builtin_amdgcn_s_setprio(1);
#pragma unroll
        for (int mi = 0; mi < 2; mi++)
#pragma unroll
          for (int nt = 0; nt < 4; nt++)
            s_[mi][nt] = mfma16(aQ[mi][kc], bK[nt], s_[mi][nt]);
        __builtin_amdgcn_s_setprio(0);
      }

      if (k0 + 63 > qb) {           // diagonal-region mask
#pragma unroll
        for (int mi = 0; mi < 2; mi++)
#pragma unroll
          for (int nt = 0; nt < 4; nt++)
#pragma unroll
            for (int r = 0; r < 4; r++) {
              int kk = k0 + nt * 16 + l15;
              int qq = qb + mi * 16 + l4 * 4 + r;
              if (kk > qq) s_[mi][nt][r] = -1e30f;
            }
      }

#pragma unroll
      for (int mi = 0; mi < 2; mi++) {
        float sf[4];
#pragma unroll
        for (int r = 0; r < 4; r++) {
          float v = fmaxf(fmaxf(s_[mi][0][r], s_[mi][1][r]), fmaxf(s_[mi][2][r], s_[mi][3][r]));
#pragma unroll
          for (int m = 1; m <= 8; m <<= 1) v = fmaxf(v, __shfl_xor(v, m));
          float mnew = fmaxf(mrun[mi][r], v);
          sf[r] = exp2f((mrun[mi][r] - mnew) * c2);
          mrun[mi][r] = mnew;
        }
        float rsum[4] = {0.f, 0.f, 0.f, 0.f};
#pragma unroll
        for (int nt = 0; nt < 4; nt++)
#pragma unroll
          for (int r = 0; r < 4; r++) {
            float p = exp2f((s_[mi][nt][r] - mrun[mi][r]) * c2);
            s_[mi][nt][r] = p;
            rsum[r] += p;
          }
#pragma unroll
        for (int r = 0; r < 4; r++) {
          float v = rsum[r];
#pragma unroll
          for (int m = 1; m <= 8; m <<= 1) v += __shfl_xor(v, m);
          lrun[mi][r] = lrun[mi][r] * sf[r] + v;
        }
#pragma unroll
        for (int dt = 0; dt < 10; dt++)
#pragma unroll
          for (int r = 0; r < 4; r++) accO[mi][dt][r] *= sf[r];
#pragma unroll
        for (int nt = 0; nt < 4; nt++)
#pragma unroll
          for (int r = 0; r < 4; r++)
            Plds[w][mi * 16 + l4 * 4 + r][nt * 16 + l15] = f2bf(s_[mi][nt][r]);
      }

      // PV: A = P (wave-local LDS), B = V rows (block LDS)
#pragma unroll
      for (int kc = 0; kc < 2; kc++) {
        bf16x8 aP[2];
#pragma unroll
        for (int mi = 0; mi < 2; mi++)
          aP[mi] = *(const bf16x8*)&Plds[w][mi * 16 + l15][kc * 32 + l4 * 8];
        bf16x8 bV[10];
#pragma unroll
        for (int dt = 0; dt < 10; dt++)
          bV[dt] = *(const bf16x8*)&Vs[dt * 16 + l15][kc * 32 + l4 * 8];
        __builtin_amdgcn_s_setprio(1);
#pragma unroll
        for (int dt = 0; dt < 10; dt++) {
          accO[0][dt] = mfma16(aP[0], bV[dt], accO[0][dt]);
          accO[1][dt] = mfma16(aP[1], bV[dt], accO[1][dt]);
        }
        __builtin_amdgcn_s_setprio(0);
      }
    }

    __builtin_amdgcn_s_barrier();   // raw: prefetch rg stays in flight
    if (more) {
#pragma unroll
      for (int i = 0; i < 10; i++) {
        int u = tid + 256 * i;
        if (u < 1280) { int row = u / 20, c = u % 20; *(uint4*)&Ks[row][c * 8] = rg[i]; }
        else { int v = u - 1280; int row = v >> 3, c = v & 7; *(uint4*)&Vs[row][c * 8] = rg[i]; }
      }
      asm volatile("s_waitcnt lgkmcnt(0)" ::: "memory");  // writes visible to other waves
    }
    __builtin_amdgcn_s_barrier();
  }

#pragma unroll
  for (int mi = 0; mi < 2; mi++) {
    float inv[4];
#pragma unroll
    for (int r = 0; r < 4; r++) inv[r] = 1.0f / lrun[mi][r];
#pragma unroll
    for (int dt = 0; dt < 10; dt++)
#pragma unroll
      for (int r = 0; r < 4; r++) {
        int q = qb + mi * 16 + l4 * 4 + r;
        ctx[(size_t)q * HID + h * HDIM + dt * 16 + l15] = f2bf(accO[mi][dt][r] * inv[r]);
      }
  }
}

// -----------------------------------------------------------------------------
extern "C" void kernel_launch(void* const* d_in, const int* in_sizes, int n_in,
                              void* d_out, int out_size, void* d_ws, size_t ws_size,
                              hipStream_t stream) {
  const float* hs    = (const float*)d_in[0];
  const float* resid = (const float*)d_in[1];
  // d_in[2] = attention_mask (causal triu) — implied by kernel, ignored
  const float* Wq  = (const float*)d_in[3];
  const float* Wkv = (const float*)d_in[4];
  const float* Wd  = (const float*)d_in[5];
  const float* bd  = (const float*)d_in[6];
  float* out = (float*)d_out;

  char* ws = (char*)d_ws;
  const size_t SH = (size_t)S_LEN * HID;          // 10,485,760
  u16* Xb     = (u16*)(ws);                        size_t off = SH * 2;
  u16* Wqkvb  = (u16*)(ws + off);                  off += (size_t)3 * HID * HID * 2; // [Wq rows | Wkv rows]
  u16* Wdb    = (u16*)(ws + off);                  off += (size_t)HID * HID * 2;
  u16* QKVraw = (u16*)(ws + off);                  off += (size_t)S_LEN * NQKV * 2;  // [2048][15360]
  u16* Qr     = (u16*)(ws + off);                  off += SH * 2;
  u16* Kr     = (u16*)(ws + off);                  off += SH * 2;
  u16* Vt     = (u16*)(ws + off);                  off += SH * 2;
  u16* ctx    = (u16*)(ws + off);                  off += SH * 2;
  float2* tab = (float2*)(ws + off);               off += (size_t)S_LEN * 80 * 8;

  // 1) one fused f32->bf16 pass: hs + Wq + Wkv + Wd
  cvt_all_kernel<<<2048, 256, 0, stream>>>(hs, Wq, Wkv, Wd, Xb, Wqkvb, Wdb);

  // 2) RoPE table
  rope_table_kernel<<<64, 256, 0, stream>>>(tab);

  // 3) fused QKV projection: [2048,15360] = Xb @ [Wq|Wkv]^T  (256x128 tiles)
  gemm256<0><<<dim3(NQKV / 128, S_LEN / 256), 512, 0, stream>>>(
      Xb, Wqkvb, QKVraw, S_LEN, NQKV, HID, nullptr, nullptr);

  // 4) RoPE Q+K in one launch; V transpose
  rope_apply2_kernel<<<2 * S_LEN * NHEAD * 80 / 256, 256, 0, stream>>>(QKVraw, tab, Qr, Kr);
  vtrans_kernel<<<dim3(S_LEN / 64, NHEAD), 256, 0, stream>>>(QKVraw + HID + HDIM, Vt, NQKV);

  // 5) attention (4 waves x 32 q-rows, balanced pairing, raw barriers)
  attn_kernel<<<512, 256, 0, stream>>>(Qr, Kr, Vt, ctx);

  // 6) output projection + bias + residual (m97 128² tile, 640 blocks)
  gemm_bt<1><<<dim3(HID / 128, S_LEN / 128), 256, 0, stream>>>(
      ctx, Wdb, out, S_LEN, HID, HID, bd, resid);
}

// Round 16
// 885.557 us; speedup vs baseline: 4.0181x; 1.0748x over previous
//
#include <hip/hip_runtime.h>
#include <cmath>

typedef unsigned short u16;
typedef unsigned int   u32;

using bf16x8 = __attribute__((ext_vector_type(8))) short;   // 8 bf16 in 4 VGPRs
using f32x4  = __attribute__((ext_vector_type(4))) float;

#define S_LEN 2048
#define NHEAD 32
#define HDIM  160
#define HID   5120   // NHEAD*HDIM
#define NQKV  15360  // HID + 2*HID

__device__ __forceinline__ f32x4 mfma16(bf16x8 a, bf16x8 b, f32x4 c) {
  return __builtin_amdgcn_mfma_f32_16x16x32_bf16(a, b, c, 0, 0, 0);
}

__device__ __forceinline__ u16 f2bf(float f) {          // RNE f32->bf16
  u32 u = __builtin_bit_cast(u32, f);
  u += 0x7FFFu + ((u >> 16) & 1u);
  return (u16)(u >> 16);
}
__device__ __forceinline__ float bf2f(u16 h) {
  u32 u = ((u32)h) << 16;
  return __builtin_bit_cast(float, u);
}

// async global->LDS, 16B per lane; LDS dest is wave-uniform base + lane*16
__device__ __forceinline__ void gload16(const void* g, void* l) {
  __builtin_amdgcn_global_load_lds((const __attribute__((address_space(1))) void*)g,
                                   (__attribute__((address_space(3))) void*)l, 16, 0, 0);
}

// ---------------- fused f32 -> bf16 convert for hs + Wq + Wkv + Wd ------------
__global__ void cvt_all_kernel(const float* __restrict__ hs, const float* __restrict__ Wq,
                               const float* __restrict__ Wkv, const float* __restrict__ Wd,
                               u16* __restrict__ Xb, u16* __restrict__ Wqkvb,
                               u16* __restrict__ Wdb) {
  const int n_hs = S_LEN * HID / 8;          // 1,310,720
  const int n_q  = HID * HID / 8;            // 3,276,800
  const int n_kv = 2 * HID * HID / 8;        // 6,553,600
  const int n_d  = HID * HID / 8;            // 3,276,800
  const int total = n_hs + n_q + n_kv + n_d; // 14,417,920
  for (int i = blockIdx.x * 256 + threadIdx.x; i < total; i += gridDim.x * 256) {
    const float* src; u16* dst; int j = i;
    if (j < n_hs)                { src = hs;  dst = Xb; }
    else if ((j -= n_hs) < n_q)  { src = Wq;  dst = Wqkvb; }
    else if ((j -= n_q) < n_kv)  { src = Wkv; dst = Wqkvb + (size_t)HID * HID; }
    else { j -= n_kv;              src = Wd;  dst = Wdb; }
    float4 a = ((const float4*)src)[(size_t)j * 2];
    float4 b = ((const float4*)src)[(size_t)j * 2 + 1];
    uint4 o;
    o.x = (u32)f2bf(a.x) | ((u32)f2bf(a.y) << 16);
    o.y = (u32)f2bf(a.z) | ((u32)f2bf(a.w) << 16);
    o.z = (u32)f2bf(b.x) | ((u32)f2bf(b.y) << 16);
    o.w = (u32)f2bf(b.z) | ((u32)f2bf(b.w) << 16);
    ((uint4*)dst)[j] = o;
  }
}

// ---------------- RoPE table: tab[s][j] = (cos, sin), j<80 -------------------
// eff=8192 -> mscale=1.0, ntk_alpha=3, base=10000*3^(160/158).
__global__ void rope_table_kernel(float2* __restrict__ tab) {
  __shared__ double invf_s[80];
  int tid = threadIdx.x;
  if (tid < 80) {
    double base = 10000.0 * pow(3.0, 160.0 / 158.0);
    invf_s[tid] = pow(base, -((double)(2 * tid)) / 160.0);
  }
  __syncthreads();
  for (int i = blockIdx.x * 256 + tid; i < S_LEN * 80; i += gridDim.x * 256) {
    int s = i / 80, j = i % 80;
    double ang = fmod((double)s * invf_s[j], 6.283185307179586476925287);
    float a = (float)ang;
    tab[i] = make_float2(cosf(a), sinf(a));
  }
}

// ---------------- RoPE apply (Q and K in one launch) + head-major relayout ----
__global__ void rope_apply2_kernel(const u16* __restrict__ qkv, const float2* __restrict__ tab,
                                   u16* __restrict__ Qr, u16* __restrict__ Kr) {
  const int n = S_LEN * NHEAD * 80;                 // per-slice dword-pairs
  int i = blockIdx.x * 256 + threadIdx.x;
  bool isK = i >= n;
  if (isK) i -= n;
  const u16* src = qkv + (isK ? HID : 0);
  int headStride = isK ? 2 * HDIM : HDIM;
  u16* dst = isK ? Kr : Qr;

  int dp = i % 80; int sh = i / 80; int h = sh % NHEAD; int s = sh / NHEAD;
  int d = 2 * dp;
  const u16* row = src + (size_t)s * NQKV + h * headStride;
  u32 q01 = *(const u32*)&row[d];
  u32 p01 = *(const u32*)&row[d < 80 ? d + 80 : d - 80];
  int j = (d < 80) ? d : d - 80;
  float2 cs0 = tab[s * 80 + j];
  float2 cs1 = tab[s * 80 + j + 1];
  float q0 = bf2f((u16)(q01 & 0xffff)), q1 = bf2f((u16)(q01 >> 16));
  float p0 = bf2f((u16)(p01 & 0xffff)), p1 = bf2f((u16)(p01 >> 16));
  float sgn = (d < 80) ? -1.f : 1.f;                // out = x*cos + rot_half(x)*sin
  float o0 = q0 * cs0.x + sgn * p0 * cs0.y;
  float o1 = q1 * cs1.x + sgn * p1 * cs1.y;
  u32 o = (u32)f2bf(o0) | ((u32)f2bf(o1) << 16);
  *(u32*)&dst[((size_t)h * S_LEN + s) * HDIM + d] = o;
}

// ---------------- V transpose: v-slice of fused QKV -> Vt[h][d][s] -----------
__global__ void vtrans_kernel(const u16* __restrict__ src, u16* __restrict__ Vt, int rowStride) {
  __shared__ u16 T[HDIM][72];                       // pad 64->72 (2-way max on reads)
  int h = blockIdx.y; int s0 = blockIdx.x * 64; int tid = threadIdx.x;
  for (int i = tid; i < 64 * 80; i += 256) {
    int s = i / 80, dp = i % 80;
    u32 v = *(const u32*)&src[(size_t)(s0 + s) * rowStride + h * 320 + 2 * dp];
    T[2 * dp][s]     = (u16)(v & 0xffff);
    T[2 * dp + 1][s] = (u16)(v >> 16);
  }
  __syncthreads();
  for (int i = tid; i < HDIM * 32; i += 256) {
    int d = i / 32, sp = i % 32;
    u32 v = (u32)T[d][2 * sp] | ((u32)T[d][2 * sp + 1] << 16);
    *(u32*)&Vt[((size_t)h * HDIM + d) * S_LEN + s0 + 2 * sp] = v;
  }
}

// ---------------- GEMM 256(M)x128(N), BK=32, 2 blocks/CU ----------------------
// R11/R12-measured 845 TF (Occupancy 42%, 0 conflicts, VGPR 56). FROZEN at
// (512,4): R13 proved (512,6) forces acc spill (13 GB scratch, 3.1 ms).
template<int EPI>
__global__ __launch_bounds__(512, 4) void gemm256(
    const u16* __restrict__ A, const u16* __restrict__ Bm, void* __restrict__ Cout,
    int M, int N, int K, const float* __restrict__ bias, const float* __restrict__ resid)
{
  __shared__ u16 As[2][8192];    // [dbuf][256 rows x 32 cols]  16 KB/buf
  __shared__ u16 Bs[2][4096];    // [dbuf][128 rows x 32 cols]   8 KB/buf
  int tid = threadIdx.x;
  int w = tid >> 6, l = tid & 63, l15 = l & 15, l4 = l >> 4;
  int wr = w >> 1, wc = w & 1;   // 4 x 2 wave grid of 64x64 tiles

  int nbx = gridDim.x;
  int nwg = nbx * gridDim.y;
  int lin = blockIdx.y * nbx + blockIdx.x;
  int cpx = nwg >> 3;
  int swz = (lin & 7) * cpx + (lin >> 3);
  int bm = (swz / nbx) * 256, bn = (swz % nbx) * 128;

  int srow = tid >> 2;                                  // 0..127
  int scol = ((tid & 3) * 8) ^ ((srow & 8) ? 16 : 0);   // pre-swizzled source col
  const u16* gA0 = A + (size_t)(bm + srow) * K + scol;  // A rows 0..127
  const u16* gA1 = gA0 + (size_t)128 * K;               // A rows 128..255
  const u16* gB  = Bm + (size_t)(bn + srow) * K + scol; // B rows 0..127
  int w512 = w * 512;                                   // wave-uniform dest (elems)

  f32x4 acc[4][4];
#pragma unroll
  for (int i = 0; i < 4; i++)
#pragma unroll
    for (int j = 0; j < 4; j++) acc[i][j] = f32x4{0.f, 0.f, 0.f, 0.f};

  int cA = (l4 * 8) ^ ((l15 & 8) ? 16 : 0);             // read-side swizzle (const)
  const int NT = K >> 5;                                // 160 for K=5120
  int arow = wr * 64;
  int brow = wc * 64;

  auto STAGE = [&](int kt) { int p = kt & 1, ko = kt << 5;
    gload16(gA0 + ko, &As[p][w512]);
    gload16(gA1 + ko, &As[p][4096 + w512]);
    gload16(gB  + ko, &Bs[p][w512]);
  };

  STAGE(0);
  for (int kt = 0; kt < NT; ++kt) {
    int p = kt & 1;
    if (kt + 1 < NT) {
      STAGE(kt + 1);                       // writes buf p^1 (reads done iter kt-1)
      asm volatile("s_waitcnt vmcnt(3)" ::: "memory");   // tile kt landed (this wave)
    } else {
      asm volatile("s_waitcnt vmcnt(0)" ::: "memory");
    }
    __builtin_amdgcn_s_barrier();          // all waves' tile-kt loads visible

    bf16x8 aF[4], bF[4];
#pragma unroll
    for (int mi = 0; mi < 4; ++mi)
      aF[mi] = *(const bf16x8*)&As[p][(arow + mi * 16 + l15) * 32 + cA];
#pragma unroll
    for (int ni = 0; ni < 4; ++ni)
      bF[ni] = *(const bf16x8*)&Bs[p][(brow + ni * 16 + l15) * 32 + cA];
    __builtin_amdgcn_s_setprio(1);
#pragma unroll
    for (int mi = 0; mi < 4; ++mi)
#pragma unroll
      for (int ni = 0; ni < 4; ++ni)
        acc[mi][ni] = mfma16(aF[mi], bF[ni], acc[mi][ni]);
    __builtin_amdgcn_s_setprio(0);
    __builtin_amdgcn_s_barrier();          // tile-kt reads complete block-wide
  }

#pragma unroll
  for (int mi = 0; mi < 4; ++mi)
#pragma unroll
    for (int ni = 0; ni < 4; ++ni) {
      int row0 = bm + wr * 64 + mi * 16 + l4 * 4;
      int col  = bn + wc * 64 + ni * 16 + l15;
      if (EPI == 0) {
        u16* C = (u16*)Cout;
#pragma unroll
        for (int r = 0; r < 4; r++) C[(size_t)(row0 + r) * N + col] = f2bf(acc[mi][ni][r]);
      } else {
        float* C = (float*)Cout;
        float b = bias[col];
#pragma unroll
        for (int r = 0; r < 4; r++) {
          size_t idx = (size_t)(row0 + r) * N + col;
          C[idx] = acc[mi][ni][r] + b + resid[idx];
        }
      }
    }
}

// ---------------- GEMM 128x128 (m97 structure; proj) -------------------------
// R12-measured best (R14 proved the dbuf+swizzle variant is 13 µs slower).
template<int EPI>
__global__ __launch_bounds__(256, 2) void gemm_bt(
    const u16* __restrict__ A, const u16* __restrict__ Bm, void* __restrict__ Cout,
    int M, int N, int K, const float* __restrict__ bias, const float* __restrict__ resid)
{
  int tid = threadIdx.x;
  int wv = tid >> 6, l = tid & 63, l15 = l & 15, l4 = l >> 4;
  int nbx = gridDim.x;
  int nwg = nbx * gridDim.y;
  int lin = blockIdx.y * nbx + blockIdx.x;
  int cpx = nwg >> 3;
  int swz = (lin & 7) * cpx + (lin >> 3);
  int bm = (swz / nbx) * 128, bn = (swz % nbx) * 128;

  __shared__ u16 As[128 * 32], Bs[128 * 32];
  f32x4 acc[4][4];
#pragma unroll
  for (int i = 0; i < 4; i++)
#pragma unroll
    for (int j = 0; j < 4; j++) acc[i][j] = f32x4{0.f, 0.f, 0.f, 0.f};

  int wm = (wv >> 1) * 64, wn = (wv & 1) * 64;
  const u16* gA = A + (size_t)(bm + (tid >> 2)) * K + (tid & 3) * 8;
  const u16* gB = Bm + (size_t)(bn + (tid >> 2)) * K + (tid & 3) * 8;
  u16* ldsA = As + wv * 16 * 32;
  u16* ldsB = Bs + wv * 16 * 32;

  for (int k0 = 0; k0 < K; k0 += 32) {
    __syncthreads();
    gload16(gA + k0, ldsA);
    gload16(gA + (size_t)64 * K + k0, ldsA + 64 * 32);
    gload16(gB + k0, ldsB);
    gload16(gB + (size_t)64 * K + k0, ldsB + 64 * 32);
    __syncthreads();
    bf16x8 af[4], bfr[4];
#pragma unroll
    for (int i = 0; i < 4; i++) af[i] = *(const bf16x8*)&As[(wm + i * 16 + l15) * 32 + l4 * 8];
#pragma unroll
    for (int i = 0; i < 4; i++) bfr[i] = *(const bf16x8*)&Bs[(wn + i * 16 + l15) * 32 + l4 * 8];
#pragma unroll
    for (int mi = 0; mi < 4; mi++)
#pragma unroll
      for (int ni = 0; ni < 4; ni++) acc[mi][ni] = mfma16(af[mi], bfr[ni], acc[mi][ni]);
  }

#pragma unroll
  for (int mi = 0; mi < 4; mi++)
#pragma unroll
    for (int ni = 0; ni < 4; ni++) {
      int row0 = bm + wm + mi * 16 + l4 * 4;
      int col  = bn + wn + ni * 16 + l15;
      if (EPI == 0) {
        u16* C = (u16*)Cout;
#pragma unroll
        for (int r = 0; r < 4; r++) C[(size_t)(row0 + r) * N + col] = f2bf(acc[mi][ni][r]);
      } else {
        float* C = (float*)Cout;
        float b = bias[col];
#pragma unroll
        for (int r = 0; r < 4; r++) {
          size_t idx = (size_t)(row0 + r) * N + col;
          C[idx] = acc[mi][ni][r] + b + resid[idx];
        }
      }
    }
}

// ---------------- Flash attention v6: K staged in LDS, V from L2 --------------
// Same 512 blocks / 4 waves x 32 q-rows / heavy+light pairing as v5. V is NOT
// staged: head->XCD pinning (lin%8 == h%8) makes each XCD's V working set
// 4 heads x 640 KB = 2.56 MB <= 4 MB L2, so PV B-fragments are L2-hits
// (guide common-mistake #7 / m169: staging cache-resident data is overhead).
// Halves staging traffic (rg[10]->rg[5]) and removes V's LDS write+read from
// the per-tile critical path. LDS 38.4 KB.
__global__ __launch_bounds__(256, 2) void attn_kernel(
    const u16* __restrict__ Qr, const u16* __restrict__ Kr,
    const u16* __restrict__ Vt, u16* __restrict__ ctx)
{
  int lin = blockIdx.x;
  int h  = lin & 31;               // same head -> same XCD (lin%8 == h%8 both halves)
  int qx = (lin < 256) ? (15 - (lin >> 5)) : ((lin - 256) >> 5);
  int q0 = qx * 128;
  int tid = threadIdx.x;
  int w = tid >> 6, l = tid & 63, l15 = l & 15, l4 = l >> 4;
  int qb = q0 + w * 32;            // wave owns 32 q-rows

  __shared__ u16 Ks[64][164];      // 328B row stride: <=2-way on frag reads
  __shared__ u16 Plds[4][32][68];  // per-wave P tile (32 rows)

  const u16* Qh = Qr + (size_t)h * S_LEN * HDIM;
  const u16* Kh = Kr + (size_t)h * S_LEN * HDIM;
  const u16* Vh = Vt + (size_t)h * HDIM * S_LEN;

  bf16x8 aQ[2][5];
#pragma unroll
  for (int mi = 0; mi < 2; mi++)
#pragma unroll
    for (int kc = 0; kc < 5; kc++)
      aQ[mi][kc] = *(const bf16x8*)&Qh[(size_t)(qb + mi * 16 + l15) * HDIM + kc * 32 + l4 * 8];

  f32x4 accO[2][10];
#pragma unroll
  for (int mi = 0; mi < 2; mi++)
#pragma unroll
    for (int dt = 0; dt < 10; dt++) accO[mi][dt] = f32x4{0.f, 0.f, 0.f, 0.f};
  float mrun[2][4], lrun[2][4];
#pragma unroll
  for (int mi = 0; mi < 2; mi++)
#pragma unroll
    for (int r = 0; r < 4; r++) { mrun[mi][r] = -1e30f; lrun[mi][r] = 0.f; }

  const float c2 = 0.07905694150420949f * 1.44269504088896f;  // 1/sqrt(160)*log2(e)
  int Tend = 2 * qx + 2;           // k tiles cover k <= q0+127

  // K staging map: 1280 16B-chunks (64 rows x 20); 256 threads -> 5 chunks each.
  {
    uint4 rg[5];
#pragma unroll
    for (int i = 0; i < 5; i++) {
      int u = tid + 256 * i;
      int row = u / 20, c = u % 20;
      rg[i] = *(const uint4*)&Kh[(size_t)row * HDIM + c * 8];
    }
#pragma unroll
    for (int i = 0; i < 5; i++) {
      int u = tid + 256 * i;
      int row = u / 20, c = u % 20;
      *(uint4*)&Ks[row][c * 8] = rg[i];
    }
  }
  __syncthreads();

  for (int t = 0; t < Tend; ++t) {
    int k0 = t * 64;
    bool more = (t + 1 < Tend);
    uint4 rg[5];
    if (more) {                     // issue next K-tile loads early (T14)
      int k1 = k0 + 64;
#pragma unroll
      for (int i = 0; i < 5; i++) {
        int u = tid + 256 * i;
        int row = u / 20, c = u % 20;
        rg[i] = *(const uint4*)&Kh[(size_t)(k1 + row) * HDIM + c * 8];
      }
    }

    if (k0 <= qb + 31) {            // wave-active (causal tile skip)
      f32x4 s_[2][4];
#pragma unroll
      for (int mi = 0; mi < 2; mi++)
#pragma unroll
        for (int nt = 0; nt < 4; nt++) s_[mi][nt] = f32x4{0.f, 0.f, 0.f, 0.f};

#pragma unroll
      for (int kc = 0; kc < 5; kc++) {
        bf16x8 bK[4];
#pragma unroll
        for (int nt = 0; nt < 4; nt++)
          bK[nt] = *(const bf16x8*)&Ks[nt * 16 + l15][kc * 32 + l4 * 8];
        __builtin_amdgcn_s_setprio(1);
#pragma unroll
        for (int mi = 0; mi < 2; mi++)
#pragma unroll
          for (int nt = 0; nt < 4; nt++)
            s_[mi][nt] = mfma16(aQ[mi][kc], bK[nt], s_[mi][nt]);
        __builtin_amdgcn_s_setprio(0);
      }

      if (k0 + 63 > qb) {           // diagonal-region mask
#pragma unroll
        for (int mi = 0; mi < 2; mi++)
#pragma unroll
          for (int nt = 0; nt < 4; nt++)
#pragma unroll
            for (int r = 0; r < 4; r++) {
              int kk = k0 + nt * 16 + l15;
              int qq = qb + mi * 16 + l4 * 4 + r;
              if (kk > qq) s_[mi][nt][r] = -1e30f;
            }
      }

#pragma unroll
      for (int mi = 0; mi < 2; mi++) {
        float sf[4];
#pragma unroll
        for (int r = 0; r < 4; r++) {
          float v = fmaxf(fmaxf(s_[mi][0][r], s_[mi][1][r]), fmaxf(s_[mi][2][r], s_[mi][3][r]));
#pragma unroll
          for (int m = 1; m <= 8; m <<= 1) v = fmaxf(v, __shfl_xor(v, m));
          float mnew = fmaxf(mrun[mi][r], v);
          sf[r] = exp2f((mrun[mi][r] - mnew) * c2);
          mrun[mi][r] = mnew;
        }
        float rsum[4] = {0.f, 0.f, 0.f, 0.f};
#pragma unroll
        for (int nt = 0; nt < 4; nt++)
#pragma unroll
          for (int r = 0; r < 4; r++) {
            float p = exp2f((s_[mi][nt][r] - mrun[mi][r]) * c2);
            s_[mi][nt][r] = p;
            rsum[r] += p;
          }
#pragma unroll
        for (int r = 0; r < 4; r++) {
          float v = rsum[r];
#pragma unroll
          for (int m = 1; m <= 8; m <<= 1) v += __shfl_xor(v, m);
          lrun[mi][r] = lrun[mi][r] * sf[r] + v;
        }
#pragma unroll
        for (int dt = 0; dt < 10; dt++)
#pragma unroll
          for (int r = 0; r < 4; r++) accO[mi][dt][r] *= sf[r];
#pragma unroll
        for (int nt = 0; nt < 4; nt++)
#pragma unroll
          for (int r = 0; r < 4; r++)
            Plds[w][mi * 16 + l4 * 4 + r][nt * 16 + l15] = f2bf(s_[mi][nt][r]);
      }

      // PV: A = P (wave-local LDS), B = Vt rows direct from global (L2-hit:
      // 4 heads/XCD x 640 KB = 2.56 MB <= 4 MB per-XCD L2)
#pragma unroll
      for (int kc = 0; kc < 2; kc++) {
        bf16x8 aP[2];
#pragma unroll
        for (int mi = 0; mi < 2; mi++)
          aP[mi] = *(const bf16x8*)&Plds[w][mi * 16 + l15][kc * 32 + l4 * 8];
        bf16x8 bV[10];
#pragma unroll
        for (int dt = 0; dt < 10; dt++)
          bV[dt] = *(const bf16x8*)&Vh[(size_t)(dt * 16 + l15) * S_LEN + k0 + kc * 32 + l4 * 8];
        __builtin_amdgcn_s_setprio(1);
#pragma unroll
        for (int dt = 0; dt < 10; dt++) {
          accO[0][dt] = mfma16(aP[0], bV[dt], accO[0][dt]);
          accO[1][dt] = mfma16(aP[1], bV[dt], accO[1][dt]);
        }
        __builtin_amdgcn_s_setprio(0);
      }
    }

    __builtin_amdgcn_s_barrier();   // raw: K prefetch rg stays in flight
    if (more) {
#pragma unroll
      for (int i = 0; i < 5; i++) {
        int u = tid + 256 * i;
        int row = u / 20, c = u % 20;
        *(uint4*)&Ks[row][c * 8] = rg[i];
      }
      asm volatile("s_waitcnt lgkmcnt(0)" ::: "memory");  // writes visible to other waves
    }
    __builtin_amdgcn_s_barrier();
  }

#pragma unroll
  for (int mi = 0; mi < 2; mi++) {
    float inv[4];
#pragma unroll
    for (int r = 0; r < 4; r++) inv[r] = 1.0f / lrun[mi][r];
#pragma unroll
    for (int dt = 0; dt < 10; dt++)
#pragma unroll
      for (int r = 0; r < 4; r++) {
        int q = qb + mi * 16 + l4 * 4 + r;
        ctx[(size_t)q * HID + h * HDIM + dt * 16 + l15] = f2bf(accO[mi][dt][r] * inv[r]);
      }
  }
}

// -----------------------------------------------------------------------------
extern "C" void kernel_launch(void* const* d_in, const int* in_sizes, int n_in,
                              void* d_out, int out_size, void* d_ws, size_t ws_size,
                              hipStream_t stream) {
  const float* hs    = (const float*)d_in[0];
  const float* resid = (const float*)d_in[1];
  // d_in[2] = attention_mask (causal triu) — implied by kernel, ignored
  const float* Wq  = (const float*)d_in[3];
  const float* Wkv = (const float*)d_in[4];
  const float* Wd  = (const float*)d_in[5];
  const float* bd  = (const float*)d_in[6];
  float* out = (float*)d_out;

  char* ws = (char*)d_ws;
  const size_t SH = (size_t)S_LEN * HID;          // 10,485,760
  u16* Xb     = (u16*)(ws);                        size_t off = SH * 2;
  u16* Wqkvb  = (u16*)(ws + off);                  off += (size_t)3 * HID * HID * 2; // [Wq rows | Wkv rows]
  u16* Wdb    = (u16*)(ws + off);                  off += (size_t)HID * HID * 2;
  u16* QKVraw = (u16*)(ws + off);                  off += (size_t)S_LEN * NQKV * 2;  // [2048][15360]
  u16* Qr     = (u16*)(ws + off);                  off += SH * 2;
  u16* Kr     = (u16*)(ws + off);                  off += SH * 2;
  u16* Vt     = (u16*)(ws + off);                  off += SH * 2;
  u16* ctx    = (u16*)(ws + off);                  off += SH * 2;
  float2* tab = (float2*)(ws + off);               off += (size_t)S_LEN * 80 * 8;

  // 1) one fused f32->bf16 pass: hs + Wq + Wkv + Wd
  cvt_all_kernel<<<2048, 256, 0, stream>>>(hs, Wq, Wkv, Wd, Xb, Wqkvb, Wdb);

  // 2) RoPE table
  rope_table_kernel<<<64, 256, 0, stream>>>(tab);

  // 3) fused QKV projection: [2048,15360] = Xb @ [Wq|Wkv]^T  (256x128 tiles)
  gemm256<0><<<dim3(NQKV / 128, S_LEN / 256), 512, 0, stream>>>(
      Xb, Wqkvb, QKVraw, S_LEN, NQKV, HID, nullptr, nullptr);

  // 4) RoPE Q+K in one launch; V transpose
  rope_apply2_kernel<<<2 * S_LEN * NHEAD * 80 / 256, 256, 0, stream>>>(QKVraw, tab, Qr, Kr);
  vtrans_kernel<<<dim3(S_LEN / 64, NHEAD), 256, 0, stream>>>(QKVraw + HID + HDIM, Vt, NQKV);

  // 5) attention (K staged, V from L2, balanced pairing, raw barriers)
  attn_kernel<<<512, 256, 0, stream>>>(Qr, Kr, Vt, ctx);

  // 6) output projection + bias + residual (m97 128² tile, 640 blocks)
  gemm_bt<1><<<dim3(HID / 128, S_LEN / 128), 256, 0, stream>>>(
      ctx, Wdb, out, S_LEN, HID, HID, bd, resid);
}

// Round 17
// 870.712 us; speedup vs baseline: 4.0866x; 1.0170x over previous
//
#include <hip/hip_runtime.h>
#include <cmath>

typedef unsigned short u16;
typedef unsigned int   u32;

using bf16x8 = __attribute__((ext_vector_type(8))) short;   // 8 bf16 in 4 VGPRs
using f32x4  = __attribute__((ext_vector_type(4))) float;

#define S_LEN 2048
#define NHEAD 32
#define HDIM  160
#define HID   5120   // NHEAD*HDIM
#define NQKV  15360  // HID + 2*HID

__device__ __forceinline__ f32x4 mfma16(bf16x8 a, bf16x8 b, f32x4 c) {
  return __builtin_amdgcn_mfma_f32_16x16x32_bf16(a, b, c, 0, 0, 0);
}

__device__ __forceinline__ u16 f2bf(float f) {          // RNE f32->bf16
  u32 u = __builtin_bit_cast(u32, f);
  u += 0x7FFFu + ((u >> 16) & 1u);
  return (u16)(u >> 16);
}
__device__ __forceinline__ float bf2f(u16 h) {
  u32 u = ((u32)h) << 16;
  return __builtin_bit_cast(float, u);
}

// async global->LDS, 16B per lane; LDS dest is wave-uniform base + lane*16
__device__ __forceinline__ void gload16(const void* g, void* l) {
  __builtin_amdgcn_global_load_lds((const __attribute__((address_space(1))) void*)g,
                                   (__attribute__((address_space(3))) void*)l, 16, 0, 0);
}

// ---------------- fused f32 -> bf16 convert for hs + Wq + Wkv + Wd ------------
__global__ void cvt_all_kernel(const float* __restrict__ hs, const float* __restrict__ Wq,
                               const float* __restrict__ Wkv, const float* __restrict__ Wd,
                               u16* __restrict__ Xb, u16* __restrict__ Wqkvb,
                               u16* __restrict__ Wdb) {
  const int n_hs = S_LEN * HID / 8;          // 1,310,720
  const int n_q  = HID * HID / 8;            // 3,276,800
  const int n_kv = 2 * HID * HID / 8;        // 6,553,600
  const int n_d  = HID * HID / 8;            // 3,276,800
  const int total = n_hs + n_q + n_kv + n_d; // 14,417,920
  for (int i = blockIdx.x * 256 + threadIdx.x; i < total; i += gridDim.x * 256) {
    const float* src; u16* dst; int j = i;
    if (j < n_hs)                { src = hs;  dst = Xb; }
    else if ((j -= n_hs) < n_q)  { src = Wq;  dst = Wqkvb; }
    else if ((j -= n_q) < n_kv)  { src = Wkv; dst = Wqkvb + (size_t)HID * HID; }
    else { j -= n_kv;              src = Wd;  dst = Wdb; }
    float4 a = ((const float4*)src)[(size_t)j * 2];
    float4 b = ((const float4*)src)[(size_t)j * 2 + 1];
    uint4 o;
    o.x = (u32)f2bf(a.x) | ((u32)f2bf(a.y) << 16);
    o.y = (u32)f2bf(a.z) | ((u32)f2bf(a.w) << 16);
    o.z = (u32)f2bf(b.x) | ((u32)f2bf(b.y) << 16);
    o.w = (u32)f2bf(b.z) | ((u32)f2bf(b.w) << 16);
    ((uint4*)dst)[j] = o;
  }
}

// ---------------- RoPE table: tab[s][j] = (cos, sin), j<80 -------------------
// eff=8192 -> mscale=1.0, ntk_alpha=3, base=10000*3^(160/158).
__global__ void rope_table_kernel(float2* __restrict__ tab) {
  __shared__ double invf_s[80];
  int tid = threadIdx.x;
  if (tid < 80) {
    double base = 10000.0 * pow(3.0, 160.0 / 158.0);
    invf_s[tid] = pow(base, -((double)(2 * tid)) / 160.0);
  }
  __syncthreads();
  for (int i = blockIdx.x * 256 + tid; i < S_LEN * 80; i += gridDim.x * 256) {
    int s = i / 80, j = i % 80;
    double ang = fmod((double)s * invf_s[j], 6.283185307179586476925287);
    float a = (float)ang;
    tab[i] = make_float2(cosf(a), sinf(a));
  }
}

// ---------------- RoPE apply (Q and K in one launch) + head-major relayout ----
__global__ void rope_apply2_kernel(const u16* __restrict__ qkv, const float2* __restrict__ tab,
                                   u16* __restrict__ Qr, u16* __restrict__ Kr) {
  const int n = S_LEN * NHEAD * 80;                 // per-slice dword-pairs
  int i = blockIdx.x * 256 + threadIdx.x;
  bool isK = i >= n;
  if (isK) i -= n;
  const u16* src = qkv + (isK ? HID : 0);
  int headStride = isK ? 2 * HDIM : HDIM;
  u16* dst = isK ? Kr : Qr;

  int dp = i % 80; int sh = i / 80; int h = sh % NHEAD; int s = sh / NHEAD;
  int d = 2 * dp;
  const u16* row = src + (size_t)s * NQKV + h * headStride;
  u32 q01 = *(const u32*)&row[d];
  u32 p01 = *(const u32*)&row[d < 80 ? d + 80 : d - 80];
  int j = (d < 80) ? d : d - 80;
  float2 cs0 = tab[s * 80 + j];
  float2 cs1 = tab[s * 80 + j + 1];
  float q0 = bf2f((u16)(q01 & 0xffff)), q1 = bf2f((u16)(q01 >> 16));
  float p0 = bf2f((u16)(p01 & 0xffff)), p1 = bf2f((u16)(p01 >> 16));
  float sgn = (d < 80) ? -1.f : 1.f;                // out = x*cos + rot_half(x)*sin
  float o0 = q0 * cs0.x + sgn * p0 * cs0.y;
  float o1 = q1 * cs1.x + sgn * p1 * cs1.y;
  u32 o = (u32)f2bf(o0) | ((u32)f2bf(o1) << 16);
  *(u32*)&dst[((size_t)h * S_LEN + s) * HDIM + d] = o;
}

// ---------------- V transpose: v-slice of fused QKV -> Vt[h][d][s] -----------
__global__ void vtrans_kernel(const u16* __restrict__ src, u16* __restrict__ Vt, int rowStride) {
  __shared__ u16 T[HDIM][72];                       // pad 64->72 (2-way max on reads)
  int h = blockIdx.y; int s0 = blockIdx.x * 64; int tid = threadIdx.x;
  for (int i = tid; i < 64 * 80; i += 256) {
    int s = i / 80, dp = i % 80;
    u32 v = *(const u32*)&src[(size_t)(s0 + s) * rowStride + h * 320 + 2 * dp];
    T[2 * dp][s]     = (u16)(v & 0xffff);
    T[2 * dp + 1][s] = (u16)(v >> 16);
  }
  __syncthreads();
  for (int i = tid; i < HDIM * 32; i += 256) {
    int d = i / 32, sp = i % 32;
    u32 v = (u32)T[d][2 * sp] | ((u32)T[d][2 * sp + 1] << 16);
    *(u32*)&Vt[((size_t)h * HDIM + d) * S_LEN + s0 + 2 * sp] = v;
  }
}

// ---------------- GEMM 256(M)x128(N), BK=32, 2 blocks/CU ----------------------
// R11/R12-measured 845 TF (Occupancy 42%, 0 conflicts, VGPR 56). FROZEN at
// (512,4): R13 proved (512,6) forces acc spill (13 GB scratch, 3.1 ms).
template<int EPI>
__global__ __launch_bounds__(512, 4) void gemm256(
    const u16* __restrict__ A, const u16* __restrict__ Bm, void* __restrict__ Cout,
    int M, int N, int K, const float* __restrict__ bias, const float* __restrict__ resid)
{
  __shared__ u16 As[2][8192];    // [dbuf][256 rows x 32 cols]  16 KB/buf
  __shared__ u16 Bs[2][4096];    // [dbuf][128 rows x 32 cols]   8 KB/buf
  int tid = threadIdx.x;
  int w = tid >> 6, l = tid & 63, l15 = l & 15, l4 = l >> 4;
  int wr = w >> 1, wc = w & 1;   // 4 x 2 wave grid of 64x64 tiles

  int nbx = gridDim.x;
  int nwg = nbx * gridDim.y;
  int lin = blockIdx.y * nbx + blockIdx.x;
  int cpx = nwg >> 3;
  int swz = (lin & 7) * cpx + (lin >> 3);
  int bm = (swz / nbx) * 256, bn = (swz % nbx) * 128;

  int srow = tid >> 2;                                  // 0..127
  int scol = ((tid & 3) * 8) ^ ((srow & 8) ? 16 : 0);   // pre-swizzled source col
  const u16* gA0 = A + (size_t)(bm + srow) * K + scol;  // A rows 0..127
  const u16* gA1 = gA0 + (size_t)128 * K;               // A rows 128..255
  const u16* gB  = Bm + (size_t)(bn + srow) * K + scol; // B rows 0..127
  int w512 = w * 512;                                   // wave-uniform dest (elems)

  f32x4 acc[4][4];
#pragma unroll
  for (int i = 0; i < 4; i++)
#pragma unroll
    for (int j = 0; j < 4; j++) acc[i][j] = f32x4{0.f, 0.f, 0.f, 0.f};

  int cA = (l4 * 8) ^ ((l15 & 8) ? 16 : 0);             // read-side swizzle (const)
  const int NT = K >> 5;                                // 160 for K=5120
  int arow = wr * 64;
  int brow = wc * 64;

  auto STAGE = [&](int kt) { int p = kt & 1, ko = kt << 5;
    gload16(gA0 + ko, &As[p][w512]);
    gload16(gA1 + ko, &As[p][4096 + w512]);
    gload16(gB  + ko, &Bs[p][w512]);
  };

  STAGE(0);
  for (int kt = 0; kt < NT; ++kt) {
    int p = kt & 1;
    if (kt + 1 < NT) {
      STAGE(kt + 1);                       // writes buf p^1 (reads done iter kt-1)
      asm volatile("s_waitcnt vmcnt(3)" ::: "memory");   // tile kt landed (this wave)
    } else {
      asm volatile("s_waitcnt vmcnt(0)" ::: "memory");
    }
    __builtin_amdgcn_s_barrier();          // all waves' tile-kt loads visible

    bf16x8 aF[4], bF[4];
#pragma unroll
    for (int mi = 0; mi < 4; ++mi)
      aF[mi] = *(const bf16x8*)&As[p][(arow + mi * 16 + l15) * 32 + cA];
#pragma unroll
    for (int ni = 0; ni < 4; ++ni)
      bF[ni] = *(const bf16x8*)&Bs[p][(brow + ni * 16 + l15) * 32 + cA];
    __builtin_amdgcn_s_setprio(1);
#pragma unroll
    for (int mi = 0; mi < 4; ++mi)
#pragma unroll
      for (int ni = 0; ni < 4; ++ni)
        acc[mi][ni] = mfma16(aF[mi], bF[ni], acc[mi][ni]);
    __builtin_amdgcn_s_setprio(0);
    __builtin_amdgcn_s_barrier();          // tile-kt reads complete block-wide
  }

#pragma unroll
  for (int mi = 0; mi < 4; ++mi)
#pragma unroll
    for (int ni = 0; ni < 4; ++ni) {
      int row0 = bm + wr * 64 + mi * 16 + l4 * 4;
      int col  = bn + wc * 64 + ni * 16 + l15;
      if (EPI == 0) {
        u16* C = (u16*)Cout;
#pragma unroll
        for (int r = 0; r < 4; r++) C[(size_t)(row0 + r) * N + col] = f2bf(acc[mi][ni][r]);
      } else {
        float* C = (float*)Cout;
        float b = bias[col];
#pragma unroll
        for (int r = 0; r < 4; r++) {
          size_t idx = (size_t)(row0 + r) * N + col;
          C[idx] = acc[mi][ni][r] + b + resid[idx];
        }
      }
    }
}

// ---------------- GEMM 128x128 (m97 structure; proj) -------------------------
// R12-measured best (R14 proved the dbuf+swizzle variant is 13 µs slower).
template<int EPI>
__global__ __launch_bounds__(256, 2) void gemm_bt(
    const u16* __restrict__ A, const u16* __restrict__ Bm, void* __restrict__ Cout,
    int M, int N, int K, const float* __restrict__ bias, const float* __restrict__ resid)
{
  int tid = threadIdx.x;
  int wv = tid >> 6, l = tid & 63, l15 = l & 15, l4 = l >> 4;
  int nbx = gridDim.x;
  int nwg = nbx * gridDim.y;
  int lin = blockIdx.y * nbx + blockIdx.x;
  int cpx = nwg >> 3;
  int swz = (lin & 7) * cpx + (lin >> 3);
  int bm = (swz / nbx) * 128, bn = (swz % nbx) * 128;

  __shared__ u16 As[128 * 32], Bs[128 * 32];
  f32x4 acc[4][4];
#pragma unroll
  for (int i = 0; i < 4; i++)
#pragma unroll
    for (int j = 0; j < 4; j++) acc[i][j] = f32x4{0.f, 0.f, 0.f, 0.f};

  int wm = (wv >> 1) * 64, wn = (wv & 1) * 64;
  const u16* gA = A + (size_t)(bm + (tid >> 2)) * K + (tid & 3) * 8;
  const u16* gB = Bm + (size_t)(bn + (tid >> 2)) * K + (tid & 3) * 8;
  u16* ldsA = As + wv * 16 * 32;
  u16* ldsB = Bs + wv * 16 * 32;

  for (int k0 = 0; k0 < K; k0 += 32) {
    __syncthreads();
    gload16(gA + k0, ldsA);
    gload16(gA + (size_t)64 * K + k0, ldsA + 64 * 32);
    gload16(gB + k0, ldsB);
    gload16(gB + (size_t)64 * K + k0, ldsB + 64 * 32);
    __syncthreads();
    bf16x8 af[4], bfr[4];
#pragma unroll
    for (int i = 0; i < 4; i++) af[i] = *(const bf16x8*)&As[(wm + i * 16 + l15) * 32 + l4 * 8];
#pragma unroll
    for (int i = 0; i < 4; i++) bfr[i] = *(const bf16x8*)&Bs[(wn + i * 16 + l15) * 32 + l4 * 8];
#pragma unroll
    for (int mi = 0; mi < 4; mi++)
#pragma unroll
      for (int ni = 0; ni < 4; ni++) acc[mi][ni] = mfma16(af[mi], bfr[ni], acc[mi][ni]);
  }

#pragma unroll
  for (int mi = 0; mi < 4; mi++)
#pragma unroll
    for (int ni = 0; ni < 4; ni++) {
      int row0 = bm + wm + mi * 16 + l4 * 4;
      int col  = bn + wn + ni * 16 + l15;
      if (EPI == 0) {
        u16* C = (u16*)Cout;
#pragma unroll
        for (int r = 0; r < 4; r++) C[(size_t)(row0 + r) * N + col] = f2bf(acc[mi][ni][r]);
      } else {
        float* C = (float*)Cout;
        float b = bias[col];
#pragma unroll
        for (int r = 0; r < 4; r++) {
          size_t idx = (size_t)(row0 + r) * N + col;
          C[idx] = acc[mi][ni][r] + b + resid[idx];
        }
      }
    }
}

// ---------------- Flash attention v7: barrier-free, K and V from L2 -----------
// R16 proved V-from-L2 (+60 µs); v7 extends it to K. Per-XCD instantaneous hot
// set = a few tiles x 4 heads << 4 MB L2. With no shared LDS buffers there are
// NO barriers at all: 8 independent waves/CU self-hide L2 latency, and each
// wave clamps its own causal tile loop (no masked idling). Plds is wave-private
// (same-wave lgkmcnt ordering handled by compiler). LDS 17.4 KB, VGPR ~180.
__global__ __launch_bounds__(256, 2) void attn_kernel(
    const u16* __restrict__ Qr, const u16* __restrict__ Kr,
    const u16* __restrict__ Vt, u16* __restrict__ ctx)
{
  int lin = blockIdx.x;
  int h  = lin & 31;               // same head -> same XCD (lin%8 == h%8 both halves)
  int qx = (lin < 256) ? (15 - (lin >> 5)) : ((lin - 256) >> 5);
  int q0 = qx * 128;
  int tid = threadIdx.x;
  int w = tid >> 6, l = tid & 63, l15 = l & 15, l4 = l >> 4;
  int qb = q0 + w * 32;            // wave owns 32 q-rows

  __shared__ u16 Plds[4][32][68];  // per-wave P tile (32 rows)

  const u16* Qh = Qr + (size_t)h * S_LEN * HDIM;
  const u16* Kh = Kr + (size_t)h * S_LEN * HDIM;
  const u16* Vh = Vt + (size_t)h * HDIM * S_LEN;

  bf16x8 aQ[2][5];
#pragma unroll
  for (int mi = 0; mi < 2; mi++)
#pragma unroll
    for (int kc = 0; kc < 5; kc++)
      aQ[mi][kc] = *(const bf16x8*)&Qh[(size_t)(qb + mi * 16 + l15) * HDIM + kc * 32 + l4 * 8];

  f32x4 accO[2][10];
#pragma unroll
  for (int mi = 0; mi < 2; mi++)
#pragma unroll
    for (int dt = 0; dt < 10; dt++) accO[mi][dt] = f32x4{0.f, 0.f, 0.f, 0.f};
  float mrun[2][4], lrun[2][4];
#pragma unroll
  for (int mi = 0; mi < 2; mi++)
#pragma unroll
    for (int r = 0; r < 4; r++) { mrun[mi][r] = -1e30f; lrun[mi][r] = 0.f; }

  const float c2 = 0.07905694150420949f * 1.44269504088896f;  // 1/sqrt(160)*log2(e)
  int TendW = (qb + 31) / 64 + 1;  // this wave's own causal tile bound

  for (int t = 0; t < TendW; ++t) {
    int k0 = t * 64;

    f32x4 s_[2][4];
#pragma unroll
    for (int mi = 0; mi < 2; mi++)
#pragma unroll
      for (int nt = 0; nt < 4; nt++) s_[mi][nt] = f32x4{0.f, 0.f, 0.f, 0.f};

#pragma unroll
    for (int kc = 0; kc < 5; kc++) {
      bf16x8 bK[4];
#pragma unroll
      for (int nt = 0; nt < 4; nt++)
        bK[nt] = *(const bf16x8*)&Kh[(size_t)(k0 + nt * 16 + l15) * HDIM + kc * 32 + l4 * 8];
      __builtin_amdgcn_s_setprio(1);
#pragma unroll
      for (int mi = 0; mi < 2; mi++)
#pragma unroll
        for (int nt = 0; nt < 4; nt++)
          s_[mi][nt] = mfma16(aQ[mi][kc], bK[nt], s_[mi][nt]);
      __builtin_amdgcn_s_setprio(0);
    }

    if (k0 + 63 > qb) {           // diagonal-region mask
#pragma unroll
      for (int mi = 0; mi < 2; mi++)
#pragma unroll
        for (int nt = 0; nt < 4; nt++)
#pragma unroll
          for (int r = 0; r < 4; r++) {
            int kk = k0 + nt * 16 + l15;
            int qq = qb + mi * 16 + l4 * 4 + r;
            if (kk > qq) s_[mi][nt][r] = -1e30f;
          }
    }

#pragma unroll
    for (int mi = 0; mi < 2; mi++) {
      float sf[4];
#pragma unroll
      for (int r = 0; r < 4; r++) {
        float v = fmaxf(fmaxf(s_[mi][0][r], s_[mi][1][r]), fmaxf(s_[mi][2][r], s_[mi][3][r]));
#pragma unroll
        for (int m = 1; m <= 8; m <<= 1) v = fmaxf(v, __shfl_xor(v, m));
        float mnew = fmaxf(mrun[mi][r], v);
        sf[r] = exp2f((mrun[mi][r] - mnew) * c2);
        mrun[mi][r] = mnew;
      }
      float rsum[4] = {0.f, 0.f, 0.f, 0.f};
#pragma unroll
      for (int nt = 0; nt < 4; nt++)
#pragma unroll
        for (int r = 0; r < 4; r++) {
          float p = exp2f((s_[mi][nt][r] - mrun[mi][r]) * c2);
          s_[mi][nt][r] = p;
          rsum[r] += p;
        }
#pragma unroll
      for (int r = 0; r < 4; r++) {
        float v = rsum[r];
#pragma unroll
        for (int m = 1; m <= 8; m <<= 1) v += __shfl_xor(v, m);
        lrun[mi][r] = lrun[mi][r] * sf[r] + v;
      }
#pragma unroll
      for (int dt = 0; dt < 10; dt++)
#pragma unroll
        for (int r = 0; r < 4; r++) accO[mi][dt][r] *= sf[r];
#pragma unroll
      for (int nt = 0; nt < 4; nt++)
#pragma unroll
        for (int r = 0; r < 4; r++)
          Plds[w][mi * 16 + l4 * 4 + r][nt * 16 + l15] = f2bf(s_[mi][nt][r]);
    }

    // PV: A = P (wave-private LDS; compiler orders via lgkmcnt), B = Vt rows
    // direct from global (L2-hit: 4 heads/XCD, instantaneous set << 4 MB)
#pragma unroll
    for (int kc = 0; kc < 2; kc++) {
      bf16x8 aP[2];
#pragma unroll
      for (int mi = 0; mi < 2; mi++)
        aP[mi] = *(const bf16x8*)&Plds[w][mi * 16 + l15][kc * 32 + l4 * 8];
      bf16x8 bV[10];
#pragma unroll
      for (int dt = 0; dt < 10; dt++)
        bV[dt] = *(const bf16x8*)&Vh[(size_t)(dt * 16 + l15) * S_LEN + k0 + kc * 32 + l4 * 8];
      __builtin_amdgcn_s_setprio(1);
#pragma unroll
      for (int dt = 0; dt < 10; dt++) {
        accO[0][dt] = mfma16(aP[0], bV[dt], accO[0][dt]);
        accO[1][dt] = mfma16(aP[1], bV[dt], accO[1][dt]);
      }
      __builtin_amdgcn_s_setprio(0);
    }
  }

#pragma unroll
  for (int mi = 0; mi < 2; mi++) {
    float inv[4];
#pragma unroll
    for (int r = 0; r < 4; r++) inv[r] = 1.0f / lrun[mi][r];
#pragma unroll
    for (int dt = 0; dt < 10; dt++)
#pragma unroll
      for (int r = 0; r < 4; r++) {
        int q = qb + mi * 16 + l4 * 4 + r;
        ctx[(size_t)q * HID + h * HDIM + dt * 16 + l15] = f2bf(accO[mi][dt][r] * inv[r]);
      }
  }
}

// -----------------------------------------------------------------------------
extern "C" void kernel_launch(void* const* d_in, const int* in_sizes, int n_in,
                              void* d_out, int out_size, void* d_ws, size_t ws_size,
                              hipStream_t stream) {
  const float* hs    = (const float*)d_in[0];
  const float* resid = (const float*)d_in[1];
  // d_in[2] = attention_mask (causal triu) — implied by kernel, ignored
  const float* Wq  = (const float*)d_in[3];
  const float* Wkv = (const float*)d_in[4];
  const float* Wd  = (const float*)d_in[5];
  const float* bd  = (const float*)d_in[6];
  float* out = (float*)d_out;

  char* ws = (char*)d_ws;
  const size_t SH = (size_t)S_LEN * HID;          // 10,485,760
  u16* Xb     = (u16*)(ws);                        size_t off = SH * 2;
  u16* Wqkvb  = (u16*)(ws + off);                  off += (size_t)3 * HID * HID * 2; // [Wq rows | Wkv rows]
  u16* Wdb    = (u16*)(ws + off);                  off += (size_t)HID * HID * 2;
  u16* QKVraw = (u16*)(ws + off);                  off += (size_t)S_LEN * NQKV * 2;  // [2048][15360]
  u16* Qr     = (u16*)(ws + off);                  off += SH * 2;
  u16* Kr     = (u16*)(ws + off);                  off += SH * 2;
  u16* Vt     = (u16*)(ws + off);                  off += SH * 2;
  u16* ctx    = (u16*)(ws + off);                  off += SH * 2;
  float2* tab = (float2*)(ws + off);               off += (size_t)S_LEN * 80 * 8;

  // 1) one fused f32->bf16 pass: hs + Wq + Wkv + Wd
  cvt_all_kernel<<<2048, 256, 0, stream>>>(hs, Wq, Wkv, Wd, Xb, Wqkvb, Wdb);

  // 2) RoPE table
  rope_table_kernel<<<64, 256, 0, stream>>>(tab);

  // 3) fused QKV projection: [2048,15360] = Xb @ [Wq|Wkv]^T  (256x128 tiles)
  gemm256<0><<<dim3(NQKV / 128, S_LEN / 256), 512, 0, stream>>>(
      Xb, Wqkvb, QKVraw, S_LEN, NQKV, HID, nullptr, nullptr);

  // 4) RoPE Q+K in one launch; V transpose
  rope_apply2_kernel<<<2 * S_LEN * NHEAD * 80 / 256, 256, 0, stream>>>(QKVraw, tab, Qr, Kr);
  vtrans_kernel<<<dim3(S_LEN / 64, NHEAD), 256, 0, stream>>>(QKVraw + HID + HDIM, Vt, NQKV);

  // 5) attention (barrier-free, K+V from L2, balanced pairing)
  attn_kernel<<<512, 256, 0, stream>>>(Qr, Kr, Vt, ctx);

  // 6) output projection + bias + residual (m97 128² tile, 640 blocks)
  gemm_bt<1><<<dim3(HID / 128, S_LEN / 128), 256, 0, stream>>>(
      ctx, Wdb, out, S_LEN, HID, HID, bd, resid);
}

// Round 18
// 868.899 us; speedup vs baseline: 4.0951x; 1.0021x over previous
//
#include <hip/hip_runtime.h>
#include <cmath>

typedef unsigned short u16;
typedef unsigned int   u32;

using bf16x8 = __attribute__((ext_vector_type(8))) short;   // 8 bf16 in 4 VGPRs
using f32x4  = __attribute__((ext_vector_type(4))) float;

#define S_LEN 2048
#define NHEAD 32
#define HDIM  160
#define HID   5120   // NHEAD*HDIM
#define NQKV  15360  // HID + 2*HID

__device__ __forceinline__ f32x4 mfma16(bf16x8 a, bf16x8 b, f32x4 c) {
  return __builtin_amdgcn_mfma_f32_16x16x32_bf16(a, b, c, 0, 0, 0);
}

__device__ __forceinline__ u16 f2bf(float f) {          // RNE f32->bf16
  u32 u = __builtin_bit_cast(u32, f);
  u += 0x7FFFu + ((u >> 16) & 1u);
  return (u16)(u >> 16);
}
__device__ __forceinline__ float bf2f(u16 h) {
  u32 u = ((u32)h) << 16;
  return __builtin_bit_cast(float, u);
}

// async global->LDS, 16B per lane; LDS dest is wave-uniform base + lane*16
__device__ __forceinline__ void gload16(const void* g, void* l) {
  __builtin_amdgcn_global_load_lds((const __attribute__((address_space(1))) void*)g,
                                   (__attribute__((address_space(3))) void*)l, 16, 0, 0);
}

// ---------------- fused f32 -> bf16 convert for hs + Wq + Wkv + Wd ------------
__global__ void cvt_all_kernel(const float* __restrict__ hs, const float* __restrict__ Wq,
                               const float* __restrict__ Wkv, const float* __restrict__ Wd,
                               u16* __restrict__ Xb, u16* __restrict__ Wqkvb,
                               u16* __restrict__ Wdb) {
  const int n_hs = S_LEN * HID / 8;          // 1,310,720
  const int n_q  = HID * HID / 8;            // 3,276,800
  const int n_kv = 2 * HID * HID / 8;        // 6,553,600
  const int n_d  = HID * HID / 8;            // 3,276,800
  const int total = n_hs + n_q + n_kv + n_d; // 14,417,920
  for (int i = blockIdx.x * 256 + threadIdx.x; i < total; i += gridDim.x * 256) {
    const float* src; u16* dst; int j = i;
    if (j < n_hs)                { src = hs;  dst = Xb; }
    else if ((j -= n_hs) < n_q)  { src = Wq;  dst = Wqkvb; }
    else if ((j -= n_q) < n_kv)  { src = Wkv; dst = Wqkvb + (size_t)HID * HID; }
    else { j -= n_kv;              src = Wd;  dst = Wdb; }
    float4 a = ((const float4*)src)[(size_t)j * 2];
    float4 b = ((const float4*)src)[(size_t)j * 2 + 1];
    uint4 o;
    o.x = (u32)f2bf(a.x) | ((u32)f2bf(a.y) << 16);
    o.y = (u32)f2bf(a.z) | ((u32)f2bf(a.w) << 16);
    o.z = (u32)f2bf(b.x) | ((u32)f2bf(b.y) << 16);
    o.w = (u32)f2bf(b.z) | ((u32)f2bf(b.w) << 16);
    ((uint4*)dst)[j] = o;
  }
}

// ---------------- RoPE table: tab[s][j] = (cos, sin), j<80 -------------------
// eff=8192 -> mscale=1.0, ntk_alpha=3, base=10000*3^(160/158).
__global__ void rope_table_kernel(float2* __restrict__ tab) {
  __shared__ double invf_s[80];
  int tid = threadIdx.x;
  if (tid < 80) {
    double base = 10000.0 * pow(3.0, 160.0 / 158.0);
    invf_s[tid] = pow(base, -((double)(2 * tid)) / 160.0);
  }
  __syncthreads();
  for (int i = blockIdx.x * 256 + tid; i < S_LEN * 80; i += gridDim.x * 256) {
    int s = i / 80, j = i % 80;
    double ang = fmod((double)s * invf_s[j], 6.283185307179586476925287);
    float a = (float)ang;
    tab[i] = make_float2(cosf(a), sinf(a));
  }
}

// ---------------- RoPE apply (Q and K in one launch) + head-major relayout ----
__global__ void rope_apply2_kernel(const u16* __restrict__ qkv, const float2* __restrict__ tab,
                                   u16* __restrict__ Qr, u16* __restrict__ Kr) {
  const int n = S_LEN * NHEAD * 80;                 // per-slice dword-pairs
  int i = blockIdx.x * 256 + threadIdx.x;
  bool isK = i >= n;
  if (isK) i -= n;
  const u16* src = qkv + (isK ? HID : 0);
  int headStride = isK ? 2 * HDIM : HDIM;
  u16* dst = isK ? Kr : Qr;

  int dp = i % 80; int sh = i / 80; int h = sh % NHEAD; int s = sh / NHEAD;
  int d = 2 * dp;
  const u16* row = src + (size_t)s * NQKV + h * headStride;
  u32 q01 = *(const u32*)&row[d];
  u32 p01 = *(const u32*)&row[d < 80 ? d + 80 : d - 80];
  int j = (d < 80) ? d : d - 80;
  float2 cs0 = tab[s * 80 + j];
  float2 cs1 = tab[s * 80 + j + 1];
  float q0 = bf2f((u16)(q01 & 0xffff)), q1 = bf2f((u16)(q01 >> 16));
  float p0 = bf2f((u16)(p01 & 0xffff)), p1 = bf2f((u16)(p01 >> 16));
  float sgn = (d < 80) ? -1.f : 1.f;                // out = x*cos + rot_half(x)*sin
  float o0 = q0 * cs0.x + sgn * p0 * cs0.y;
  float o1 = q1 * cs1.x + sgn * p1 * cs1.y;
  u32 o = (u32)f2bf(o0) | ((u32)f2bf(o1) << 16);
  *(u32*)&dst[((size_t)h * S_LEN + s) * HDIM + d] = o;
}

// ---------------- V transpose: v-slice of fused QKV -> Vt[h][d][s] -----------
__global__ void vtrans_kernel(const u16* __restrict__ src, u16* __restrict__ Vt, int rowStride) {
  __shared__ u16 T[HDIM][72];                       // pad 64->72 (2-way max on reads)
  int h = blockIdx.y; int s0 = blockIdx.x * 64; int tid = threadIdx.x;
  for (int i = tid; i < 64 * 80; i += 256) {
    int s = i / 80, dp = i % 80;
    u32 v = *(const u32*)&src[(size_t)(s0 + s) * rowStride + h * 320 + 2 * dp];
    T[2 * dp][s]     = (u16)(v & 0xffff);
    T[2 * dp + 1][s] = (u16)(v >> 16);
  }
  __syncthreads();
  for (int i = tid; i < HDIM * 32; i += 256) {
    int d = i / 32, sp = i % 32;
    u32 v = (u32)T[d][2 * sp] | ((u32)T[d][2 * sp + 1] << 16);
    *(u32*)&Vt[((size_t)h * HDIM + d) * S_LEN + s0 + 2 * sp] = v;
  }
}

// ---------------- GEMM 256(M)x128(N), BK=32, tri-buffer, 1 barrier/iter -------
// Upgrade over R11/R12 (845 TF, 2 barriers/iter): 3 LDS buffers (72 KB, still
// 2 blocks/CU) let the end-of-iter barrier be dropped. STAGE(kt+2) is issued
// AFTER barrier kt and targets buf[(kt+2)%3] == buf[(kt-1)%3], whose readers
// (compute kt-1) drained their ds_reads before reaching barrier kt -> race-free
// with ONE barrier/iter. Prefetch depth 2 (6 loads in flight); vmcnt(3) at iter
// top proves tile kt landed while kt+1 stays in flight (T4, never drain).
// FROZEN at (512,4): R13 proved tighter bounds spill acc.
template<int EPI>
__global__ __launch_bounds__(512, 4) void gemm256(
    const u16* __restrict__ A, const u16* __restrict__ Bm, void* __restrict__ Cout,
    int M, int N, int K, const float* __restrict__ bias, const float* __restrict__ resid)
{
  __shared__ u16 As[3][8192];    // [tri-buf][256 rows x 32 cols]  48 KB
  __shared__ u16 Bs[3][4096];    // [tri-buf][128 rows x 32 cols]  24 KB
  int tid = threadIdx.x;
  int w = tid >> 6, l = tid & 63, l15 = l & 15, l4 = l >> 4;
  int wr = w >> 1, wc = w & 1;   // 4 x 2 wave grid of 64x64 tiles

  int nbx = gridDim.x;
  int nwg = nbx * gridDim.y;
  int lin = blockIdx.y * nbx + blockIdx.x;
  int cpx = nwg >> 3;
  int swz = (lin & 7) * cpx + (lin >> 3);
  int bm = (swz / nbx) * 256, bn = (swz % nbx) * 128;

  int srow = tid >> 2;                                  // 0..127
  int scol = ((tid & 3) * 8) ^ ((srow & 8) ? 16 : 0);   // pre-swizzled source col
  const u16* gA0 = A + (size_t)(bm + srow) * K + scol;  // A rows 0..127
  const u16* gA1 = gA0 + (size_t)128 * K;               // A rows 128..255
  const u16* gB  = Bm + (size_t)(bn + srow) * K + scol; // B rows 0..127
  int w512 = w * 512;                                   // wave-uniform dest (elems)

  f32x4 acc[4][4];
#pragma unroll
  for (int i = 0; i < 4; i++)
#pragma unroll
    for (int j = 0; j < 4; j++) acc[i][j] = f32x4{0.f, 0.f, 0.f, 0.f};

  int cA = (l4 * 8) ^ ((l15 & 8) ? 16 : 0);             // read-side swizzle (const)
  const int NT = K >> 5;                                // 160 for K=5120
  int arow = wr * 64;
  int brow = wc * 64;

  auto STAGE = [&](int kt, int p) { int ko = kt << 5;
    gload16(gA0 + ko, &As[p][w512]);
    gload16(gA1 + ko, &As[p][4096 + w512]);
    gload16(gB  + ko, &Bs[p][w512]);
  };

  STAGE(0, 0);
  STAGE(1, 1);                           // NT >= 2 always (K=5120)
  int pc = 0;                            // kt % 3
  for (int kt = 0; kt < NT; ++kt) {
    if (kt + 1 < NT)
      asm volatile("s_waitcnt vmcnt(3)" ::: "memory");   // tile kt landed; kt+1 in flight
    else
      asm volatile("s_waitcnt vmcnt(0)" ::: "memory");
    __builtin_amdgcn_s_barrier();        // all waves' tile-kt loads visible AND
                                         // all waves' kt-1 ds_reads drained
    if (kt + 2 < NT) {
      int ps = (pc + 2 >= 3) ? pc - 1 : pc + 2;          // (kt+2) % 3
      STAGE(kt + 2, ps);                 // overwrites buf[(kt-1)%3]: safe (see hdr)
    }

    bf16x8 aF[4], bF[4];
#pragma unroll
    for (int mi = 0; mi < 4; ++mi)
      aF[mi] = *(const bf16x8*)&As[pc][(arow + mi * 16 + l15) * 32 + cA];
#pragma unroll
    for (int ni = 0; ni < 4; ++ni)
      bF[ni] = *(const bf16x8*)&Bs[pc][(brow + ni * 16 + l15) * 32 + cA];
    __builtin_amdgcn_s_setprio(1);
#pragma unroll
    for (int mi = 0; mi < 4; ++mi)
#pragma unroll
      for (int ni = 0; ni < 4; ++ni)
        acc[mi][ni] = mfma16(aF[mi], bF[ni], acc[mi][ni]);
    __builtin_amdgcn_s_setprio(0);

    pc = (pc + 1 == 3) ? 0 : pc + 1;
  }

#pragma unroll
  for (int mi = 0; mi < 4; ++mi)
#pragma unroll
    for (int ni = 0; ni < 4; ++ni) {
      int row0 = bm + wr * 64 + mi * 16 + l4 * 4;
      int col  = bn + wc * 64 + ni * 16 + l15;
      if (EPI == 0) {
        u16* C = (u16*)Cout;
#pragma unroll
        for (int r = 0; r < 4; r++) C[(size_t)(row0 + r) * N + col] = f2bf(acc[mi][ni][r]);
      } else {
        float* C = (float*)Cout;
        float b = bias[col];
#pragma unroll
        for (int r = 0; r < 4; r++) {
          size_t idx = (size_t)(row0 + r) * N + col;
          C[idx] = acc[mi][ni][r] + b + resid[idx];
        }
      }
    }
}

// ---------------- GEMM 128x128 (m97 structure; proj) -------------------------
// R12-measured best (R14 proved the dbuf+swizzle variant is 13 µs slower).
template<int EPI>
__global__ __launch_bounds__(256, 2) void gemm_bt(
    const u16* __restrict__ A, const u16* __restrict__ Bm, void* __restrict__ Cout,
    int M, int N, int K, const float* __restrict__ bias, const float* __restrict__ resid)
{
  int tid = threadIdx.x;
  int wv = tid >> 6, l = tid & 63, l15 = l & 15, l4 = l >> 4;
  int nbx = gridDim.x;
  int nwg = nbx * gridDim.y;
  int lin = blockIdx.y * nbx + blockIdx.x;
  int cpx = nwg >> 3;
  int swz = (lin & 7) * cpx + (lin >> 3);
  int bm = (swz / nbx) * 128, bn = (swz % nbx) * 128;

  __shared__ u16 As[128 * 32], Bs[128 * 32];
  f32x4 acc[4][4];
#pragma unroll
  for (int i = 0; i < 4; i++)
#pragma unroll
    for (int j = 0; j < 4; j++) acc[i][j] = f32x4{0.f, 0.f, 0.f, 0.f};

  int wm = (wv >> 1) * 64, wn = (wv & 1) * 64;
  const u16* gA = A + (size_t)(bm + (tid >> 2)) * K + (tid & 3) * 8;
  const u16* gB = Bm + (size_t)(bn + (tid >> 2)) * K + (tid & 3) * 8;
  u16* ldsA = As + wv * 16 * 32;
  u16* ldsB = Bs + wv * 16 * 32;

  for (int k0 = 0; k0 < K; k0 += 32) {
    __syncthreads();
    gload16(gA + k0, ldsA);
    gload16(gA + (size_t)64 * K + k0, ldsA + 64 * 32);
    gload16(gB + k0, ldsB);
    gload16(gB + (size_t)64 * K + k0, ldsB + 64 * 32);
    __syncthreads();
    bf16x8 af[4], bfr[4];
#pragma unroll
    for (int i = 0; i < 4; i++) af[i] = *(const bf16x8*)&As[(wm + i * 16 + l15) * 32 + l4 * 8];
#pragma unroll
    for (int i = 0; i < 4; i++) bfr[i] = *(const bf16x8*)&Bs[(wn + i * 16 + l15) * 32 + l4 * 8];
#pragma unroll
    for (int mi = 0; mi < 4; mi++)
#pragma unroll
      for (int ni = 0; ni < 4; ni++) acc[mi][ni] = mfma16(af[mi], bfr[ni], acc[mi][ni]);
  }

#pragma unroll
  for (int mi = 0; mi < 4; mi++)
#pragma unroll
    for (int ni = 0; ni < 4; ni++) {
      int row0 = bm + wm + mi * 16 + l4 * 4;
      int col  = bn + wn + ni * 16 + l15;
      if (EPI == 0) {
        u16* C = (u16*)Cout;
#pragma unroll
        for (int r = 0; r < 4; r++) C[(size_t)(row0 + r) * N + col] = f2bf(acc[mi][ni][r]);
      } else {
        float* C = (float*)Cout;
        float b = bias[col];
#pragma unroll
        for (int r = 0; r < 4; r++) {
          size_t idx = (size_t)(row0 + r) * N + col;
          C[idx] = acc[mi][ni][r] + b + resid[idx];
        }
      }
    }
}

// ---------------- Flash attention v7: barrier-free, K and V from L2 -----------
// R16/R17-proven: head->XCD pinning keeps K,V L2-resident; no LDS staging, no
// barriers; 8 independent waves/CU self-hide latency; per-wave causal clamp.
__global__ __launch_bounds__(256, 2) void attn_kernel(
    const u16* __restrict__ Qr, const u16* __restrict__ Kr,
    const u16* __restrict__ Vt, u16* __restrict__ ctx)
{
  int lin = blockIdx.x;
  int h  = lin & 31;               // same head -> same XCD (lin%8 == h%8 both halves)
  int qx = (lin < 256) ? (15 - (lin >> 5)) : ((lin - 256) >> 5);
  int q0 = qx * 128;
  int tid = threadIdx.x;
  int w = tid >> 6, l = tid & 63, l15 = l & 15, l4 = l >> 4;
  int qb = q0 + w * 32;            // wave owns 32 q-rows

  __shared__ u16 Plds[4][32][68];  // per-wave P tile (32 rows)

  const u16* Qh = Qr + (size_t)h * S_LEN * HDIM;
  const u16* Kh = Kr + (size_t)h * S_LEN * HDIM;
  const u16* Vh = Vt + (size_t)h * HDIM * S_LEN;

  bf16x8 aQ[2][5];
#pragma unroll
  for (int mi = 0; mi < 2; mi++)
#pragma unroll
    for (int kc = 0; kc < 5; kc++)
      aQ[mi][kc] = *(const bf16x8*)&Qh[(size_t)(qb + mi * 16 + l15) * HDIM + kc * 32 + l4 * 8];

  f32x4 accO[2][10];
#pragma unroll
  for (int mi = 0; mi < 2; mi++)
#pragma unroll
    for (int dt = 0; dt < 10; dt++) accO[mi][dt] = f32x4{0.f, 0.f, 0.f, 0.f};
  float mrun[2][4], lrun[2][4];
#pragma unroll
  for (int mi = 0; mi < 2; mi++)
#pragma unroll
    for (int r = 0; r < 4; r++) { mrun[mi][r] = -1e30f; lrun[mi][r] = 0.f; }

  const float c2 = 0.07905694150420949f * 1.44269504088896f;  // 1/sqrt(160)*log2(e)
  int TendW = (qb + 31) / 64 + 1;  // this wave's own causal tile bound

  for (int t = 0; t < TendW; ++t) {
    int k0 = t * 64;

    f32x4 s_[2][4];
#pragma unroll
    for (int mi = 0; mi < 2; mi++)
#pragma unroll
      for (int nt = 0; nt < 4; nt++) s_[mi][nt] = f32x4{0.f, 0.f, 0.f, 0.f};

#pragma unroll
    for (int kc = 0; kc < 5; kc++) {
      bf16x8 bK[4];
#pragma unroll
      for (int nt = 0; nt < 4; nt++)
        bK[nt] = *(const bf16x8*)&Kh[(size_t)(k0 + nt * 16 + l15) * HDIM + kc * 32 + l4 * 8];
      __builtin_amdgcn_s_setprio(1);
#pragma unroll
      for (int mi = 0; mi < 2; mi++)
#pragma unroll
        for (int nt = 0; nt < 4; nt++)
          s_[mi][nt] = mfma16(aQ[mi][kc], bK[nt], s_[mi][nt]);
      __builtin_amdgcn_s_setprio(0);
    }

    if (k0 + 63 > qb) {           // diagonal-region mask
#pragma unroll
      for (int mi = 0; mi < 2; mi++)
#pragma unroll
        for (int nt = 0; nt < 4; nt++)
#pragma unroll
          for (int r = 0; r < 4; r++) {
            int kk = k0 + nt * 16 + l15;
            int qq = qb + mi * 16 + l4 * 4 + r;
            if (kk > qq) s_[mi][nt][r] = -1e30f;
          }
    }

#pragma unroll
    for (int mi = 0; mi < 2; mi++) {
      float sf[4];
#pragma unroll
      for (int r = 0; r < 4; r++) {
        float v = fmaxf(fmaxf(s_[mi][0][r], s_[mi][1][r]), fmaxf(s_[mi][2][r], s_[mi][3][r]));
#pragma unroll
        for (int m = 1; m <= 8; m <<= 1) v = fmaxf(v, __shfl_xor(v, m));
        float mnew = fmaxf(mrun[mi][r], v);
        sf[r] = exp2f((mrun[mi][r] - mnew) * c2);
        mrun[mi][r] = mnew;
      }
      float rsum[4] = {0.f, 0.f, 0.f, 0.f};
#pragma unroll
      for (int nt = 0; nt < 4; nt++)
#pragma unroll
        for (int r = 0; r < 4; r++) {
          float p = exp2f((s_[mi][nt][r] - mrun[mi][r]) * c2);
          s_[mi][nt][r] = p;
          rsum[r] += p;
        }
#pragma unroll
      for (int r = 0; r < 4; r++) {
        float v = rsum[r];
#pragma unroll
        for (int m = 1; m <= 8; m <<= 1) v += __shfl_xor(v, m);
        lrun[mi][r] = lrun[mi][r] * sf[r] + v;
      }
#pragma unroll
      for (int dt = 0; dt < 10; dt++)
#pragma unroll
        for (int r = 0; r < 4; r++) accO[mi][dt][r] *= sf[r];
#pragma unroll
      for (int nt = 0; nt < 4; nt++)
#pragma unroll
        for (int r = 0; r < 4; r++)
          Plds[w][mi * 16 + l4 * 4 + r][nt * 16 + l15] = f2bf(s_[mi][nt][r]);
    }

    // PV: A = P (wave-private LDS; compiler orders via lgkmcnt), B = Vt rows
    // direct from global (L2-hit: 4 heads/XCD, instantaneous set << 4 MB)
#pragma unroll
    for (int kc = 0; kc < 2; kc++) {
      bf16x8 aP[2];
#pragma unroll
      for (int mi = 0; mi < 2; mi++)
        aP[mi] = *(const bf16x8*)&Plds[w][mi * 16 + l15][kc * 32 + l4 * 8];
      bf16x8 bV[10];
#pragma unroll
      for (int dt = 0; dt < 10; dt++)
        bV[dt] = *(const bf16x8*)&Vh[(size_t)(dt * 16 + l15) * S_LEN + k0 + kc * 32 + l4 * 8];
      __builtin_amdgcn_s_setprio(1);
#pragma unroll
      for (int dt = 0; dt < 10; dt++) {
        accO[0][dt] = mfma16(aP[0], bV[dt], accO[0][dt]);
        accO[1][dt] = mfma16(aP[1], bV[dt], accO[1][dt]);
      }
      __builtin_amdgcn_s_setprio(0);
    }
  }

#pragma unroll
  for (int mi = 0; mi < 2; mi++) {
    float inv[4];
#pragma unroll
    for (int r = 0; r < 4; r++) inv[r] = 1.0f / lrun[mi][r];
#pragma unroll
    for (int dt = 0; dt < 10; dt++)
#pragma unroll
      for (int r = 0; r < 4; r++) {
        int q = qb + mi * 16 + l4 * 4 + r;
        ctx[(size_t)q * HID + h * HDIM + dt * 16 + l15] = f2bf(accO[mi][dt][r] * inv[r]);
      }
  }
}

// -----------------------------------------------------------------------------
extern "C" void kernel_launch(void* const* d_in, const int* in_sizes, int n_in,
                              void* d_out, int out_size, void* d_ws, size_t ws_size,
                              hipStream_t stream) {
  const float* hs    = (const float*)d_in[0];
  const float* resid = (const float*)d_in[1];
  // d_in[2] = attention_mask (causal triu) — implied by kernel, ignored
  const float* Wq  = (const float*)d_in[3];
  const float* Wkv = (const float*)d_in[4];
  const float* Wd  = (const float*)d_in[5];
  const float* bd  = (const float*)d_in[6];
  float* out = (float*)d_out;

  char* ws = (char*)d_ws;
  const size_t SH = (size_t)S_LEN * HID;          // 10,485,760
  u16* Xb     = (u16*)(ws);                        size_t off = SH * 2;
  u16* Wqkvb  = (u16*)(ws + off);                  off += (size_t)3 * HID * HID * 2; // [Wq rows | Wkv rows]
  u16* Wdb    = (u16*)(ws + off);                  off += (size_t)HID * HID * 2;
  u16* QKVraw = (u16*)(ws + off);                  off += (size_t)S_LEN * NQKV * 2;  // [2048][15360]
  u16* Qr     = (u16*)(ws + off);                  off += SH * 2;
  u16* Kr     = (u16*)(ws + off);                  off += SH * 2;
  u16* Vt     = (u16*)(ws + off);                  off += SH * 2;
  u16* ctx    = (u16*)(ws + off);                  off += SH * 2;
  float2* tab = (float2*)(ws + off);               off += (size_t)S_LEN * 80 * 8;

  // 1) one fused f32->bf16 pass: hs + Wq + Wkv + Wd
  cvt_all_kernel<<<2048, 256, 0, stream>>>(hs, Wq, Wkv, Wd, Xb, Wqkvb, Wdb);

  // 2) RoPE table
  rope_table_kernel<<<64, 256, 0, stream>>>(tab);

  // 3) fused QKV projection: [2048,15360] = Xb @ [Wq|Wkv]^T  (256x128 tiles)
  gemm256<0><<<dim3(NQKV / 128, S_LEN / 256), 512, 0, stream>>>(
      Xb, Wqkvb, QKVraw, S_LEN, NQKV, HID, nullptr, nullptr);

  // 4) RoPE Q+K in one launch; V transpose
  rope_apply2_kernel<<<2 * S_LEN * NHEAD * 80 / 256, 256, 0, stream>>>(QKVraw, tab, Qr, Kr);
  vtrans_kernel<<<dim3(S_LEN / 64, NHEAD), 256, 0, stream>>>(QKVraw + HID + HDIM, Vt, NQKV);

  // 5) attention (barrier-free, K+V from L2, balanced pairing)
  attn_kernel<<<512, 256, 0, stream>>>(Qr, Kr, Vt, ctx);

  // 6) output projection + bias + residual (m97 128² tile, 640 blocks)
  gemm_bt<1><<<dim3(HID / 128, S_LEN / 128), 256, 0, stream>>>(
      ctx, Wdb, out, S_LEN, HID, HID, bd, resid);
}